// Round 3
// baseline (6049.190 us; speedup 1.0000x reference)
//
#include <hip/hip_runtime.h>
#include <hip/hip_bf16.h>

// ---- problem constants ----
#define B_    1024
#define PROT_ 1218
#define CC_   8192
#define XSIDE 9410            // PROT + C
#define XROW  18820           // 2*(PROT+C)
#define MER   2567            // 2*64 + 2436 + 3
#define SON   2436            // 2*PROT
#define K2_   16384           // 2*C
#define NEGF  (-4294967295.0f)

// ================= utility: block reduce (double) =================
__device__ __forceinline__ double blk_reduce(double v, double* sm) {
    int t = threadIdx.x;
    sm[t] = v; __syncthreads();
    for (int s = blockDim.x >> 1; s > 0; s >>= 1) {
        if (t < s) sm[t] += sm[t + s];
        __syncthreads();
    }
    double r = sm[0];
    __syncthreads();
    return r;
}

// ================= generic tiled f32 GEMM =================
// C[M,N] = act(A@W + bias). ACT: 0 none, 1 relu, 2 lrelu(0.01), 3 elu
// AG: 0 plain A (row stride lda); 1 adjacency gather from X
template<int ACT, int AG>
__global__ __launch_bounds__(256) void gemm_k(
    const float* __restrict__ A, int lda,
    const float* __restrict__ W, const float* __restrict__ bias,
    float* __restrict__ C, int M, int N, int K)
{
    __shared__ float As[16][65];
    __shared__ float Ws[16][65];
    const int tid = threadIdx.x;
    const int tx = tid & 15, ty = tid >> 4;
    const int row0 = blockIdx.y * 64, col0 = blockIdx.x * 64;
    float acc[4][4] = {};
    for (int kt = 0; kt < K; kt += 16) {
#pragma unroll
        for (int i = 0; i < 4; i++) {
            int idx = tid + i * 256;
            int m = idx >> 4, kk = idx & 15;
            int kg = kt + kk;
            float v = 0.f;
            if (kg < K) {
                if (AG == 0) v = A[(long)(row0 + m) * lda + kg];
                else         v = A[(long)(row0 + m) * XROW + kg + (kg < CC_ ? PROT_ : SON)];
            }
            As[kk][m] = v;
        }
#pragma unroll
        for (int i = 0; i < 4; i++) {
            int idx = tid + i * 256;
            int n = idx & 63, kk = idx >> 6;
            int kg = kt + kk, cg = col0 + n;
            float v = 0.f;
            if (kg < K && cg < N) v = W[(long)kg * N + cg];
            Ws[kk][n] = v;
        }
        __syncthreads();
#pragma unroll
        for (int kk = 0; kk < 16; kk++) {
            float a[4], w[4];
#pragma unroll
            for (int i = 0; i < 4; i++) a[i] = As[kk][ty * 4 + i];
#pragma unroll
            for (int j = 0; j < 4; j++) w[j] = Ws[kk][tx * 4 + j];
#pragma unroll
            for (int i = 0; i < 4; i++)
#pragma unroll
                for (int j = 0; j < 4; j++)
                    acc[i][j] = fmaf(a[i], w[j], acc[i][j]);
        }
        __syncthreads();
    }
#pragma unroll
    for (int i = 0; i < 4; i++) {
        int r = row0 + ty * 4 + i;
#pragma unroll
        for (int j = 0; j < 4; j++) {
            int c = col0 + tx * 4 + j;
            if (c < N) {
                float v = acc[i][j] + (bias ? bias[c] : 0.f);
                if (ACT == 1)      v = fmaxf(v, 0.f);
                else if (ACT == 2) v = (v >= 0.f) ? v : 0.01f * v;
                else if (ACT == 3) v = (v > 0.f) ? v : expm1f(v);
                C[(long)r * N + c] = v;
            }
        }
    }
}

// ============ AE decoder GEMM fused with L2 loss (recon never stored) ============
__global__ __launch_bounds__(256) void gemm_l2_k(
    const float* __restrict__ A,      // t2 (1024 x 1024)
    const float* __restrict__ W,      // d1w (1024 x 16384)
    const float* __restrict__ bias,   // d1b
    const float* __restrict__ X,      // for adj gather
    double* __restrict__ l2acc, int M, int N, int K)
{
    __shared__ float As[16][65];
    __shared__ float Ws[16][65];
    __shared__ double sm[256];
    const int tid = threadIdx.x;
    const int tx = tid & 15, ty = tid >> 4;
    const int row0 = blockIdx.y * 64, col0 = blockIdx.x * 64;
    float acc[4][4] = {};
    for (int kt = 0; kt < K; kt += 16) {
#pragma unroll
        for (int i = 0; i < 4; i++) {
            int idx = tid + i * 256;
            int m = idx >> 4, kk = idx & 15;
            As[kk][m] = A[(long)(row0 + m) * K + kt + kk];
        }
#pragma unroll
        for (int i = 0; i < 4; i++) {
            int idx = tid + i * 256;
            int n = idx & 63, kk = idx >> 6;
            Ws[kk][n] = W[(long)(kt + kk) * N + col0 + n];
        }
        __syncthreads();
#pragma unroll
        for (int kk = 0; kk < 16; kk++) {
            float a[4], w[4];
#pragma unroll
            for (int i = 0; i < 4; i++) a[i] = As[kk][ty * 4 + i];
#pragma unroll
            for (int j = 0; j < 4; j++) w[j] = Ws[kk][tx * 4 + j];
#pragma unroll
            for (int i = 0; i < 4; i++)
#pragma unroll
                for (int j = 0; j < 4; j++)
                    acc[i][j] = fmaf(a[i], w[j], acc[i][j]);
        }
        __syncthreads();
    }
    double part = 0.0;
#pragma unroll
    for (int i = 0; i < 4; i++) {
        int r = row0 + ty * 4 + i;
#pragma unroll
        for (int j = 0; j < 4; j++) {
            int c = col0 + tx * 4 + j;
            float recon = acc[i][j] + bias[c];
            recon = (recon >= 0.f) ? recon : 0.01f * recon;
            float adj = X[(long)r * XROW + c + (c < CC_ ? PROT_ : SON)];
            float d = (adj - recon) * ((adj != 0.f) ? 5.f : 1.f);
            part += (double)d * (double)d;
        }
    }
    double tot = blk_reduce(part, sm);
    if (tid == 0) atomicAdd(l2acc, tot);
}

// ================= mean/var reduction over a buffer =================
__global__ __launch_bounds__(256) void meanvar_k(const float* __restrict__ src, int n,
                                                 double* __restrict__ out2)
{
    double s = 0, q = 0;
    for (long i = (long)blockIdx.x * 256 + threadIdx.x; i < n; i += (long)gridDim.x * 256) {
        float v = src[i]; s += v; q += (double)v * v;
    }
    __shared__ double sm[256];
    double ts = blk_reduce(s, sm);
    double tq = blk_reduce(q, sm);
    if (threadIdx.x == 0) { atomicAdd(&out2[0], ts); atomicAdd(&out2[1], tq); }
}

// ========== bn2d (scalar affine from sums) + 3x3 SAME conv, per-image block ==========
template<int ACC>
__global__ __launch_bounds__(256) void bnconv_k(
    const float* __restrict__ src, float* __restrict__ dst,
    const double* __restrict__ sums, const float* __restrict__ g, const float* __restrict__ bb,
    const float* __restrict__ cw, double* __restrict__ nextsums)
{
    __shared__ float tile[34 * 34];
    __shared__ float wc[9];
    __shared__ float sscale, sshift;
    __shared__ double sm[256];
    const int tid = threadIdx.x;
    if (tid == 0) {
        const double n = 1048576.0;
        double m = sums[0] / n, v = sums[1] / n - (sums[0] / n) * (sums[0] / n);
        float sc = g[0] * (float)(1.0 / sqrt(v + 1e-5));
        sscale = sc; sshift = bb[0] - (float)m * sc;
    }
    if (tid < 9) wc[tid] = cw[tid];
    for (int i = tid; i < 34 * 34; i += 256) tile[i] = 0.f;
    __syncthreads();
    const float sc = sscale, sh = sshift;
    const long base = (long)blockIdx.x * 1024;
    for (int i = tid; i < 1024; i += 256) {
        int y = i >> 5, x = i & 31;
        tile[(y + 1) * 34 + (x + 1)] = fmaf(src[base + i], sc, sh);
    }
    __syncthreads();
    double s = 0, q = 0;
    for (int i = tid; i < 1024; i += 256) {
        int y = i >> 5, x = i & 31;
        const float* t0 = &tile[y * 34 + x];
        float o = t0[0] * wc[0] + t0[1] * wc[1] + t0[2] * wc[2]
                + t0[34] * wc[3] + t0[35] * wc[4] + t0[36] * wc[5]
                + t0[68] * wc[6] + t0[69] * wc[7] + t0[70] * wc[8];
        dst[base + i] = o;
        if (ACC) { s += o; q += (double)o * o; }
    }
    if (ACC) {
        double ts = blk_reduce(s, sm);
        double tq = blk_reduce(q, sm);
        if (tid == 0) { atomicAdd(&nextsums[0], ts); atomicAdd(&nextsums[1], tq); }
    }
}

// ========== elementwise relu(bn(x)) with stats accumulation for next bn ==========
__global__ __launch_bounds__(256) void relubn_k(
    const float* __restrict__ src, float* __restrict__ dst,
    const double* __restrict__ sums, const float* __restrict__ g, const float* __restrict__ bb,
    double* __restrict__ nextsums, int n)
{
    const double nn = (double)n;
    double m = sums[0] / nn, v = sums[1] / nn - (sums[0] / nn) * (sums[0] / nn);
    float sc = g[0] * (float)(1.0 / sqrt(v + 1e-5));
    float sh = bb[0] - (float)m * sc;
    double s = 0, q = 0;
    for (long i = (long)blockIdx.x * 256 + threadIdx.x; i < n; i += (long)gridDim.x * 256) {
        float x = fmaf(src[i], sc, sh);
        x = fmaxf(x, 0.f);
        dst[i] = x;
        s += x; q += (double)x * x;
    }
    __shared__ double sm[256];
    double ts = blk_reduce(s, sm);
    double tq = blk_reduce(q, sm);
    if (threadIdx.x == 0) { atomicAdd(&nextsums[0], ts); atomicAdd(&nextsums[1], tq); }
}

// ========== fully fused dual attention + aggregation + cos/bil/lin, one block per b ==========
__global__ __launch_bounds__(256) void attn_k(
    const float* __restrict__ pg1, const float* __restrict__ pg2,
    const float* __restrict__ qw, const float* __restrict__ qb,
    const float* __restrict__ kw, const float* __restrict__ kb,
    const float* __restrict__ vw, const float* __restrict__ vb,
    const float* __restrict__ lng, const float* __restrict__ lnb,
    const float* __restrict__ bilw, const float* __restrict__ lsw, const float* __restrict__ lsb,
    float* __restrict__ merged)
{
    __shared__ float P1[1024], P2[1024];
    __shared__ float Wq[1024], Wk[1024], Wv[1024];
    __shared__ float bq[32], bk[32], bv[32], sg[32], sb[32];
    __shared__ float rs1[32], rs2[32];
    __shared__ float Qm[1024], Km[32 * 33], Vm[1024];
    __shared__ float S[128 * 33];            // also reused for bilw (64x65 fits)
    __shared__ float O[32 * 33];
    __shared__ float mrow[32], irow[32];
    __shared__ float R1[64], R2[64];

    const int tid = threadIdx.x;
    const long pb = (long)blockIdx.x * 1024;
    for (int i = tid; i < 1024; i += 256) {
        P1[i] = pg1[pb + i]; P2[i] = pg2[pb + i];
        Wq[i] = qw[i]; Wk[i] = kw[i]; Wv[i] = vw[i];
    }
    if (tid < 32) { bq[tid] = qb[tid]; bk[tid] = kb[tid]; bv[tid] = vb[tid];
                    sg[tid] = lng[tid]; sb[tid] = lnb[tid]; }
    __syncthreads();
    if (tid < 64) {
        int s_ = tid & 31; bool two = tid >= 32;
        const float* P = two ? P2 : P1;
        float sum = 0;
        for (int f = 0; f < 32; f++) sum += P[s_ * 32 + f];
        float m = (sum != 0.f) ? 1.f : 0.f;
        if (two) rs2[s_] = m; else rs1[s_] = m;
    }
    __syncthreads();

    for (int pass = 0; pass < 2; pass++) {
        const float* Pq = pass ? P2 : P1;
        const float* Pk = pass ? P1 : P2;
        const float* qm = pass ? rs2 : rs1;
        const float* km = pass ? rs1 : rs2;
        // Q,K,V projections with relu (K stored seq-major padded stride 33)
        for (int i = tid; i < 1024; i += 256) {
            int s_ = i >> 5, n = i & 31;
            float aq = bq[n], ak = bk[n], av = bv[n];
            for (int k = 0; k < 32; k++) {
                float pq = Pq[s_ * 32 + k], pk = Pk[s_ * 32 + k];
                aq = fmaf(pq, Wq[k * 32 + n], aq);
                ak = fmaf(pk, Wk[k * 32 + n], ak);
                av = fmaf(pq, Wv[k * 32 + n], av);
            }
            Qm[i] = fmaxf(aq, 0.f);
            Km[s_ * 33 + n] = fmaxf(ak, 0.f);
            Vm[i] = fmaxf(av, 0.f);
        }
        __syncthreads();
        // scores
        for (int i = tid; i < 4096; i += 256) {
            int h = i >> 10, r = i & 1023, q = r >> 5, k = r & 31;
            float a = 0;
            for (int d = 0; d < 8; d++)
                a = fmaf(Qm[q * 32 + h * 8 + d], Km[k * 33 + h * 8 + d], a);
            a *= 0.35355339059327379f;
            if (km[k] == 0.f) a = NEGF;
            S[(h * 32 + q) * 33 + k] = a;
        }
        __syncthreads();
        // softmax (rows of 32) * query mask
        if (tid < 128) {
            int base = tid * 33, q = tid & 31;
            float mx = -3.4e38f;
            for (int k = 0; k < 32; k++) mx = fmaxf(mx, S[base + k]);
            float sum = 0;
            for (int k = 0; k < 32; k++) sum += expf(S[base + k] - mx);
            float inv = qm[q] / sum;
            for (int k = 0; k < 32; k++) S[base + k] = expf(S[base + k] - mx) * inv;
        }
        __syncthreads();
        // out = att@V + residual
        for (int i = tid; i < 1024; i += 256) {
            int s_ = i >> 5, f = i & 31, h = f >> 3;
            float a = 0;
            int sbase = (h * 32 + s_) * 33;
            for (int k = 0; k < 32; k++) a = fmaf(S[sbase + k], Vm[k * 32 + f], a);
            O[s_ * 33 + f] = a + Pq[i];
        }
        __syncthreads();
        // layernorm stats (ddof=1, std+1e-8)
        if (tid < 32) {
            float m = 0;
            for (int f = 0; f < 32; f++) m += O[tid * 33 + f];
            m *= (1.f / 32.f);
            float v = 0;
            for (int f = 0; f < 32; f++) { float d = O[tid * 33 + f] - m; v += d * d; }
            v *= (1.f / 31.f);
            mrow[tid] = m;
            irow[tid] = 1.f / (sqrtf(v) + 1e-8f);
        }
        __syncthreads();
        // a = ln(out); prod = pg * a (in place)
        for (int i = tid; i < 1024; i += 256) {
            int s_ = i >> 5, f = i & 31;
            float a = sg[f] * (O[s_ * 33 + f] - mrow[s_]) * irow[s_] + sb[f];
            O[s_ * 33 + f] = Pq[i] * a;
        }
        __syncthreads();
        // aggregate mean/max over seq
        float* R = pass ? R2 : R1;
        if (tid < 64) {
            int f = tid & 31;
            if (tid < 32) {
                float m = 0;
                for (int s_ = 0; s_ < 32; s_++) m += O[s_ * 33 + f];
                R[f] = m * (1.f / 32.f);
            } else {
                float mx = -3.4e38f;
                for (int s_ = 0; s_ < 32; s_++) mx = fmaxf(mx, O[s_ * 33 + f]);
                R[32 + f] = mx;
            }
        }
        __syncthreads();
    }
    // stage bilw into S with stride-65 padding
    for (int i = tid; i < 4096; i += 256) {
        int r = i >> 6, c = i & 63;
        S[r * 65 + c] = bilw[i];
    }
    __syncthreads();
    if (tid < 64) {
        float r1v = R1[tid], r2v = R2[tid];
        float dot = r1v * r2v, s1 = r1v * r1v, s2 = r2v * r2v;
        float u = 0;
        for (int j = 0; j < 64; j++) u = fmaf(S[tid * 65 + j], R2[j], u);
        float bilp = r1v * u;
        float linp = fmaf(r1v, lsw[tid], r2v * lsw[64 + tid]);
        for (int o = 32; o > 0; o >>= 1) {
            dot  += __shfl_down(dot, o);
            s1   += __shfl_down(s1, o);
            s2   += __shfl_down(s2, o);
            bilp += __shfl_down(bilp, o);
            linp += __shfl_down(linp, o);
        }
        const long mb = (long)blockIdx.x * MER;
        if (tid == 0) {
            float n1 = fmaxf(sqrtf(s1), 1e-8f), n2 = fmaxf(sqrtf(s2), 1e-8f);
            merged[mb + 2564] = dot / (n1 * n2);
            merged[mb + 2565] = bilp;
            merged[mb + 2566] = tanhf(linp + lsb[0]);
        }
        merged[mb + tid] = R1[tid];
        merged[mb + 64 + tid] = R2[tid];
    }
}

// ================= row norms =================
// SRC=1: concat[p1,p2] gathered from X; SRC=0: plain matrix (ld == ncols)
template<int SRC>
__global__ __launch_bounds__(256) void rownorm_k(const float* __restrict__ src,
                                                 float* __restrict__ outn, int ncols)
{
    const int b = blockIdx.x;
    double s = 0;
    for (int j = threadIdx.x; j < ncols; j += 256) {
        float v = (SRC == 1) ? src[(long)b * XROW + j + (j < PROT_ ? 0 : CC_)]
                             : src[(long)b * ncols + j];
        s += (double)v * v;
    }
    __shared__ double sm[256];
    double tot = blk_reduce(s, sm);
    if (threadIdx.x == 0) {
        float n = (float)sqrt(tot);
        outn[b] = (n == 0.f) ? 1.f : n;
    }
}

// ================= column stats (sum, sumsq) via f64 atomics =================
// SRC=0: plain (src, ld); SRC=1: X p-gather / rownorm; SRC=2: src/rownorm (ld)
template<int SRC>
__global__ __launch_bounds__(256) void colstats_k(
    const float* __restrict__ src, int ld, int ncols,
    const float* __restrict__ rownorm, double* __restrict__ stats)
{
    int col = blockIdx.x * 256 + threadIdx.x;
    if (col >= ncols) return;
    int r0 = blockIdx.y * 64;
    double s = 0, q = 0;
    for (int b = r0; b < r0 + 64; b++) {
        float v;
        if (SRC == 1)      v = src[(long)b * XROW + col + (col < PROT_ ? 0 : CC_)] / rownorm[b];
        else if (SRC == 2) v = src[(long)b * ld + col] / rownorm[b];
        else               v = src[(long)b * ld + col];
        s += v; q += (double)v * v;
    }
    atomicAdd(&stats[2 * col], s);
    atomicAdd(&stats[2 * col + 1], q);
}

// sonsen: standardize l2-normalized p columns into merged[:, 128 + j]
__global__ __launch_bounds__(256) void sonsen_k(
    const float* __restrict__ X, const float* __restrict__ pnorm,
    const double* __restrict__ stats, float* __restrict__ merged)
{
    int col = blockIdx.x * 256 + threadIdx.x;
    if (col >= SON) return;
    int b = blockIdx.y;
    float v = X[(long)b * XROW + col + (col < PROT_ ? 0 : CC_)] / pnorm[b];
    double m = stats[2 * col] * (1.0 / 1024.0);
    double var = stats[2 * col + 1] * (1.0 / 1024.0) - m * m;
    float sd = (float)sqrt(fmax(var, 0.0));
    if (sd == 0.f) sd = 1.f;
    merged[(long)b * MER + 128 + col] = (v - (float)m) / sd;
}

// merged: in-place l2row + column standardize
__global__ __launch_bounds__(256) void mtrans_k(
    float* __restrict__ mg, const float* __restrict__ mn, const double* __restrict__ st)
{
    int col = blockIdx.x * 256 + threadIdx.x;
    if (col >= MER) return;
    int b = blockIdx.y;
    double m = st[2 * col] * (1.0 / 1024.0);
    double var = st[2 * col + 1] * (1.0 / 1024.0) - m * m;
    float sd = (float)sqrt(fmax(var, 0.0));
    if (sd == 0.f) sd = 1.f;
    float v = mg[(long)b * MER + col] / mn[b];
    mg[(long)b * MER + col] = (v - (float)m) / sd;
}

// bn1d transform in place: (x-m)*rsqrt(v+1e-5)*g + b
__global__ __launch_bounds__(256) void bn1dtrans_k(
    float* __restrict__ h, int ncols, const double* __restrict__ st,
    const float* __restrict__ g, const float* __restrict__ bb)
{
    int col = blockIdx.x * 256 + threadIdx.x;
    if (col >= ncols) return;
    int b = blockIdx.y;
    double m = st[2 * col] / 1024.0;
    double var = st[2 * col + 1] / 1024.0 - m * m;
    float rs = (float)(1.0 / sqrt(var + 1e-5));
    float x = h[(long)b * ncols + col];
    h[(long)b * ncols + col] = (float)((double)x - m) * rs * g[col] + bb[col];
}

// L1 = 2*B*sum(emb^2) - 2*||sum_b emb||^2   (collapsed Gram)
__global__ __launch_bounds__(128) void l1_k(const float* __restrict__ emb, double* __restrict__ out)
{
    const int j = threadIdx.x;
    double s = 0, q = 0;
    for (int b = 0; b < 1024; b++) {
        float v = emb[b * 128 + j];
        s += v; q += (double)v * v;
    }
    __shared__ double sm[128];
    double qtot = blk_reduce(q, sm);
    double ssum = blk_reduce(s * s, sm);
    if (j == 0) out[0] = 2.0 * 1024.0 * qtot - 2.0 * ssum;
}

// final: bn1d over 2 cols + sigmoid + argmax + scalars
__global__ __launch_bounds__(1024) void final_k(
    const float* __restrict__ h4, const float* __restrict__ g2, const float* __restrict__ be2,
    const double* __restrict__ scal /* [0]=L2sum, [1]=L1 */, float* __restrict__ out)
{
    const int b = threadIdx.x;
    float x0 = h4[2 * b], x1 = h4[2 * b + 1];
    __shared__ double sm[1024];
    double red[4];
    double vals[4] = { (double)x0, (double)x0 * x0, (double)x1, (double)x1 * x1 };
    for (int p = 0; p < 4; p++) red[p] = blk_reduce(vals[p], sm);
    double m0 = red[0] / 1024.0, v0 = red[1] / 1024.0 - m0 * m0;
    double m1 = red[2] / 1024.0, v1 = red[3] / 1024.0 - m1 * m1;
    float r0 = (float)(1.0 / sqrt(v0 + 1e-5)), r1 = (float)(1.0 / sqrt(v1 + 1e-5));
    float y0 = (float)((double)x0 - m0) * r0 * g2[0] + be2[0];
    float y1 = (float)((double)x1 - m1) * r1 * g2[1] + be2[1];
    float p0 = 1.f / (1.f + expf(-y0));
    float p1 = 1.f / (1.f + expf(-y1));
    out[2 * b] = p0;
    out[2 * b + 1] = p1;
    out[2048 + b] = (p1 > p0) ? 1.f : 0.f;
    if (b == 0) {
        double L1 = scal[1], L2a = 0.1 * scal[0];
        out[3072] = (float)L1;
        out[3073] = (float)L2a;
        out[3074] = (float)(L1 + L2a);
    }
}

// ================================= host =================================
extern "C" void kernel_launch(void* const* d_in, const int* in_sizes, int n_in,
                              void* d_out, int out_size, void* d_ws, size_t ws_size,
                              hipStream_t stream)
{
    const float* X    = (const float*)d_in[0];
    const float* glw  = (const float*)d_in[1];
    const float* glb  = (const float*)d_in[2];
    const float* bnag = (const float*)d_in[3];
    const float* bnab = (const float*)d_in[4];
    const float* bn1g = (const float*)d_in[5];
    const float* bn1b = (const float*)d_in[6];
    const float* bnbg = (const float*)d_in[7];
    const float* bnbb = (const float*)d_in[8];
    const float* c1w  = (const float*)d_in[9];
    const float* c2w  = (const float*)d_in[10];
    const float* qw   = (const float*)d_in[11];
    const float* qb   = (const float*)d_in[12];
    const float* kw   = (const float*)d_in[13];
    const float* kb   = (const float*)d_in[14];
    const float* vw   = (const float*)d_in[15];
    const float* vb   = (const float*)d_in[16];
    const float* lng  = (const float*)d_in[17];
    const float* lnb  = (const float*)d_in[18];
    const float* bilw = (const float*)d_in[19];
    const float* lsw  = (const float*)d_in[20];
    const float* lsb  = (const float*)d_in[21];
    const float* e0w  = (const float*)d_in[22];
    const float* e0b  = (const float*)d_in[23];
    const float* e1w  = (const float*)d_in[24];
    const float* e1b  = (const float*)d_in[25];
    const float* d0w  = (const float*)d_in[26];
    const float* d0b  = (const float*)d_in[27];
    const float* d1w  = (const float*)d_in[28];
    const float* d1b  = (const float*)d_in[29];
    const float* cw1  = (const float*)d_in[30];
    const float* cb1  = (const float*)d_in[31];
    const float* cg1  = (const float*)d_in[32];
    const float* cbe1 = (const float*)d_in[33];
    const float* cw2  = (const float*)d_in[34];
    const float* cb2  = (const float*)d_in[35];
    const float* cw3  = (const float*)d_in[36];
    const float* cb3  = (const float*)d_in[37];
    const float* cw4  = (const float*)d_in[38];
    const float* cb4  = (const float*)d_in[39];
    const float* cg2  = (const float*)d_in[40];
    const float* cbe2 = (const float*)d_in[41];

    // ---- workspace layout ----
    double* dscr = (double*)d_ws;
    const size_t N_PST = 2 * (size_t)SON;   // 4872
    const size_t N_MST = 2 * (size_t)MER;   // 5134
    const size_t N_H1  = 2 * 512;           // 1024
    const size_t NDBL  = 14 + N_PST + N_MST + N_H1;
    double* bns  = dscr;          // [0..11] bn sums (2 sides x {gl, z1, z2} x {s, q})
    double* l2a  = dscr + 12;
    double* l1a  = dscr + 13;
    double* pst  = dscr + 14;
    double* mst  = pst + N_PST;
    double* h1st = mst + N_MST;
    float* f = (float*)(dscr + NDBL);
    float* bufA = f; f += 1048576;
    float* bufB = f; f += 1048576;
    float* pg1  = f; f += 1048576;
    float* pg2  = f; f += 1048576;
    float* emb  = f; f += 131072;
    float* mg   = f; f += (size_t)1024 * MER;
    float* h1   = f; f += 1024 * 512;
    float* h2   = f; f += 1024 * 256;
    float* h3   = f; f += 1024 * 128;
    float* h4   = f; f += 2048;
    float* pn   = f; f += 1024;
    float* mn   = f; f += 1024;
    // AE intermediates reuse the CNN staging buffers (dead after CNN chain)
    float* t    = bufA;
    float* t2   = bufB;

    hipMemsetAsync(dscr, 0, NDBL * sizeof(double), stream);

    const dim3 blk(256);

    // ---- gated CNN chain, both sides ----
    for (int s = 0; s < 2; s++) {
        const float* Xs = X + (long)s * XSIDE;
        double* s6 = bns + s * 6;
        float* pg = s ? pg2 : pg1;
        gemm_k<0, 0><<<dim3(16, 16), blk, 0, stream>>>(Xs, XROW, glw, glb, bufA, 1024, 1024, PROT_);
        meanvar_k<<<dim3(512), blk, 0, stream>>>(bufA, 1048576, s6 + 0);
        bnconv_k<1><<<dim3(1024), blk, 0, stream>>>(bufA, bufB, s6 + 0, bnag, bnab, c1w, s6 + 2);
        relubn_k<<<dim3(512), blk, 0, stream>>>(bufB, bufA, s6 + 2, bn1g, bn1b, s6 + 4, 1048576);
        bnconv_k<0><<<dim3(1024), blk, 0, stream>>>(bufA, pg, s6 + 4, bnbg, bnbb, c2w, nullptr);
    }

    // ---- attention block (r1, r2, cos, bil, lin into merged) ----
    attn_k<<<dim3(1024), blk, 0, stream>>>(pg1, pg2, qw, qb, kw, kb, vw, vb,
                                           lng, lnb, bilw, lsw, lsb, mg);

    // ---- sonsen into merged ----
    rownorm_k<1><<<dim3(1024), blk, 0, stream>>>(X, pn, SON);
    colstats_k<1><<<dim3(10, 16), blk, 0, stream>>>(X, 0, SON, pn, pst);
    sonsen_k<<<dim3(10, 1024), blk, 0, stream>>>(X, pn, pst, mg);

    // ---- merged: l2rows + scale (in place) ----
    rownorm_k<0><<<dim3(1024), blk, 0, stream>>>(mg, mn, MER);
    colstats_k<2><<<dim3(11, 16), blk, 0, stream>>>(mg, MER, MER, mn, mst);
    mtrans_k<<<dim3(11, 1024), blk, 0, stream>>>(mg, mn, mst);

    // ---- autoencoder (t, t2 alias bufA, bufB) ----
    gemm_k<2, 1><<<dim3(16, 16), blk, 0, stream>>>(X, 0, e0w, e0b, t, 1024, 1024, K2_);
    gemm_k<2, 0><<<dim3(2, 16), blk, 0, stream>>>(t, 1024, e1w, e1b, emb, 1024, 128, 1024);
    l1_k<<<dim3(1), dim3(128), 0, stream>>>(emb, l1a);
    gemm_k<2, 0><<<dim3(16, 16), blk, 0, stream>>>(emb, 128, d0w, d0b, t2, 1024, 1024, 128);
    gemm_l2_k<<<dim3(256, 16), blk, 0, stream>>>(t2, d1w, d1b, X, l2a, 1024, K2_, 1024);

    // ---- classifier ----
    gemm_k<0, 0><<<dim3(8, 16), blk, 0, stream>>>(mg, MER, cw1, cb1, h1, 1024, 512, MER);
    colstats_k<0><<<dim3(2, 16), blk, 0, stream>>>(h1, 512, 512, nullptr, h1st);
    bn1dtrans_k<<<dim3(2, 1024), blk, 0, stream>>>(h1, 512, h1st, cg1, cbe1);
    gemm_k<3, 0><<<dim3(4, 16), blk, 0, stream>>>(h1, 512, cw2, cb2, h2, 1024, 256, 512);
    gemm_k<0, 0><<<dim3(2, 16), blk, 0, stream>>>(h2, 256, cw3, cb3, h3, 1024, 128, 256);
    gemm_k<0, 0><<<dim3(1, 16), blk, 0, stream>>>(h3, 128, cw4, cb4, h4, 1024, 2, 128);

    final_k<<<dim3(1), dim3(1024), 0, stream>>>(h4, cg2, cbe2, dscr + 12, (float*)d_out);
}

// Round 4
// 2876.141 us; speedup vs baseline: 2.1032x; 2.1032x over previous
//
#include <hip/hip_runtime.h>
#include <hip/hip_bf16.h>

// ---- problem constants ----
#define B_    1024
#define PROT_ 1218
#define CC_   8192
#define XSIDE 9410            // PROT + C
#define XROW  18820           // 2*(PROT+C)
#define MER   2567            // 2*64 + 2436 + 3
#define SON   2436            // 2*PROT
#define K2_   16384           // 2*C
#define NEGF  (-4294967295.0f)

// ================= utility: block reduce (double) =================
__device__ __forceinline__ double blk_reduce(double v, double* sm) {
    int t = threadIdx.x;
    sm[t] = v; __syncthreads();
    for (int s = blockDim.x >> 1; s > 0; s >>= 1) {
        if (t < s) sm[t] += sm[t + s];
        __syncthreads();
    }
    double r = sm[0];
    __syncthreads();
    return r;
}

template<int ACT> __device__ __forceinline__ float apply_act(float v) {
    if (ACT == 1) return fmaxf(v, 0.f);
    if (ACT == 2) return (v >= 0.f) ? v : 0.01f * v;
    if (ACT == 3) return (v > 0.f) ? v : expm1f(v);
    return v;
}

// ================= split-K tiled f32 GEMM (partials via atomicAdd) =================
// C must be pre-zeroed. Bias/activation applied by bias_act_k afterwards.
// AG: 0 plain A (row stride lda); 1 adjacency gather from X
template<int AG>
__global__ __launch_bounds__(256) void gemm_sk(
    const float* __restrict__ A, int lda,
    const float* __restrict__ W,
    float* __restrict__ C, int M, int N, int K, int kc)
{
    __shared__ float As[16][65];
    __shared__ float Ws[16][65];
    const int tid = threadIdx.x;
    const int tx = tid & 15, ty = tid >> 4;
    const int row0 = blockIdx.y * 64, col0 = blockIdx.x * 64;
    const int k0 = blockIdx.z * kc;
    const int kend = min(K, k0 + kc);
    float acc[4][4] = {};
    for (int kt = k0; kt < kend; kt += 16) {
#pragma unroll
        for (int i = 0; i < 4; i++) {
            int idx = tid + i * 256;
            int m = idx >> 4, kk = idx & 15;
            int kg = kt + kk;
            float v = 0.f;
            if (kg < kend) {
                if (AG == 0) v = A[(long)(row0 + m) * lda + kg];
                else         v = A[(long)(row0 + m) * XROW + kg + (kg < CC_ ? PROT_ : SON)];
            }
            As[kk][m] = v;
        }
#pragma unroll
        for (int i = 0; i < 4; i++) {
            int idx = tid + i * 256;
            int n = idx & 63, kk = idx >> 6;
            int kg = kt + kk, cg = col0 + n;
            float v = 0.f;
            if (kg < kend && cg < N) v = W[(long)kg * N + cg];
            Ws[kk][n] = v;
        }
        __syncthreads();
#pragma unroll
        for (int kk = 0; kk < 16; kk++) {
            float a[4], w[4];
#pragma unroll
            for (int i = 0; i < 4; i++) a[i] = As[kk][ty * 4 + i];
#pragma unroll
            for (int j = 0; j < 4; j++) w[j] = Ws[kk][tx * 4 + j];
#pragma unroll
            for (int i = 0; i < 4; i++)
#pragma unroll
                for (int j = 0; j < 4; j++)
                    acc[i][j] = fmaf(a[i], w[j], acc[i][j]);
        }
        __syncthreads();
    }
#pragma unroll
    for (int i = 0; i < 4; i++) {
        int r = row0 + ty * 4 + i;
#pragma unroll
        for (int j = 0; j < 4; j++) {
            int c = col0 + tx * 4 + j;
            if (c < N) atomicAdd(&C[(long)r * N + c], acc[i][j]);
        }
    }
}

// epilogue: C = act(C + bias), vectorized float4 (N multiple of 4)
template<int ACT>
__global__ __launch_bounds__(256) void bias_act_k(float* __restrict__ C,
        const float* __restrict__ bias, int MN, int N)
{
    int i = (blockIdx.x * 256 + threadIdx.x) * 4;
    if (i >= MN) return;
    float4 v = *reinterpret_cast<float4*>(&C[i]);
    int c = i % N;
    v.x = apply_act<ACT>(v.x + bias[c]);
    v.y = apply_act<ACT>(v.y + bias[c + 1]);
    v.z = apply_act<ACT>(v.z + bias[c + 2]);
    v.w = apply_act<ACT>(v.w + bias[c + 3]);
    *reinterpret_cast<float4*>(&C[i]) = v;
}

// ================= generic tiled f32 GEMM (kept for tiny cw4) =================
template<int ACT, int AG>
__global__ __launch_bounds__(256) void gemm_k(
    const float* __restrict__ A, int lda,
    const float* __restrict__ W, const float* __restrict__ bias,
    float* __restrict__ C, int M, int N, int K)
{
    __shared__ float As[16][65];
    __shared__ float Ws[16][65];
    const int tid = threadIdx.x;
    const int tx = tid & 15, ty = tid >> 4;
    const int row0 = blockIdx.y * 64, col0 = blockIdx.x * 64;
    float acc[4][4] = {};
    for (int kt = 0; kt < K; kt += 16) {
#pragma unroll
        for (int i = 0; i < 4; i++) {
            int idx = tid + i * 256;
            int m = idx >> 4, kk = idx & 15;
            int kg = kt + kk;
            float v = 0.f;
            if (kg < K) {
                if (AG == 0) v = A[(long)(row0 + m) * lda + kg];
                else         v = A[(long)(row0 + m) * XROW + kg + (kg < CC_ ? PROT_ : SON)];
            }
            As[kk][m] = v;
        }
#pragma unroll
        for (int i = 0; i < 4; i++) {
            int idx = tid + i * 256;
            int n = idx & 63, kk = idx >> 6;
            int kg = kt + kk, cg = col0 + n;
            float v = 0.f;
            if (kg < K && cg < N) v = W[(long)kg * N + cg];
            Ws[kk][n] = v;
        }
        __syncthreads();
#pragma unroll
        for (int kk = 0; kk < 16; kk++) {
            float a[4], w[4];
#pragma unroll
            for (int i = 0; i < 4; i++) a[i] = As[kk][ty * 4 + i];
#pragma unroll
            for (int j = 0; j < 4; j++) w[j] = Ws[kk][tx * 4 + j];
#pragma unroll
            for (int i = 0; i < 4; i++)
#pragma unroll
                for (int j = 0; j < 4; j++)
                    acc[i][j] = fmaf(a[i], w[j], acc[i][j]);
        }
        __syncthreads();
    }
#pragma unroll
    for (int i = 0; i < 4; i++) {
        int r = row0 + ty * 4 + i;
#pragma unroll
        for (int j = 0; j < 4; j++) {
            int c = col0 + tx * 4 + j;
            if (c < N) {
                float v = acc[i][j] + (bias ? bias[c] : 0.f);
                if (ACT == 1)      v = fmaxf(v, 0.f);
                else if (ACT == 2) v = (v >= 0.f) ? v : 0.01f * v;
                else if (ACT == 3) v = (v > 0.f) ? v : expm1f(v);
                C[(long)r * N + c] = v;
            }
        }
    }
}

// ============ AE decoder GEMM fused with L2 loss (recon never stored) ============
__global__ __launch_bounds__(256) void gemm_l2_k(
    const float* __restrict__ A,      // t2 (1024 x 1024)
    const float* __restrict__ W,      // d1w (1024 x 16384)
    const float* __restrict__ bias,   // d1b
    const float* __restrict__ X,      // for adj gather
    double* __restrict__ l2acc, int M, int N, int K)
{
    __shared__ float As[16][65];
    __shared__ float Ws[16][65];
    __shared__ double sm[256];
    const int tid = threadIdx.x;
    const int tx = tid & 15, ty = tid >> 4;
    const int row0 = blockIdx.y * 64, col0 = blockIdx.x * 64;
    float acc[4][4] = {};
    for (int kt = 0; kt < K; kt += 16) {
#pragma unroll
        for (int i = 0; i < 4; i++) {
            int idx = tid + i * 256;
            int m = idx >> 4, kk = idx & 15;
            As[kk][m] = A[(long)(row0 + m) * K + kt + kk];
        }
#pragma unroll
        for (int i = 0; i < 4; i++) {
            int idx = tid + i * 256;
            int n = idx & 63, kk = idx >> 6;
            Ws[kk][n] = W[(long)(kt + kk) * N + col0 + n];
        }
        __syncthreads();
#pragma unroll
        for (int kk = 0; kk < 16; kk++) {
            float a[4], w[4];
#pragma unroll
            for (int i = 0; i < 4; i++) a[i] = As[kk][ty * 4 + i];
#pragma unroll
            for (int j = 0; j < 4; j++) w[j] = Ws[kk][tx * 4 + j];
#pragma unroll
            for (int i = 0; i < 4; i++)
#pragma unroll
                for (int j = 0; j < 4; j++)
                    acc[i][j] = fmaf(a[i], w[j], acc[i][j]);
        }
        __syncthreads();
    }
    double part = 0.0;
#pragma unroll
    for (int i = 0; i < 4; i++) {
        int r = row0 + ty * 4 + i;
#pragma unroll
        for (int j = 0; j < 4; j++) {
            int c = col0 + tx * 4 + j;
            float recon = acc[i][j] + bias[c];
            recon = (recon >= 0.f) ? recon : 0.01f * recon;
            float adj = X[(long)r * XROW + c + (c < CC_ ? PROT_ : SON)];
            float d = (adj - recon) * ((adj != 0.f) ? 5.f : 1.f);
            part += (double)d * (double)d;
        }
    }
    double tot = blk_reduce(part, sm);
    if (tid == 0) atomicAdd(l2acc, tot);
}

// ================= mean/var reduction over a buffer =================
__global__ __launch_bounds__(256) void meanvar_k(const float* __restrict__ src, int n,
                                                 double* __restrict__ out2)
{
    double s = 0, q = 0;
    for (long i = (long)blockIdx.x * 256 + threadIdx.x; i < n; i += (long)gridDim.x * 256) {
        float v = src[i]; s += v; q += (double)v * v;
    }
    __shared__ double sm[256];
    double ts = blk_reduce(s, sm);
    double tq = blk_reduce(q, sm);
    if (threadIdx.x == 0) { atomicAdd(&out2[0], ts); atomicAdd(&out2[1], tq); }
}

// ========== bn2d (scalar affine from sums) + 3x3 SAME conv, per-image block ==========
template<int ACC>
__global__ __launch_bounds__(256) void bnconv_k(
    const float* __restrict__ src, float* __restrict__ dst,
    const double* __restrict__ sums, const float* __restrict__ g, const float* __restrict__ bb,
    const float* __restrict__ cw, double* __restrict__ nextsums)
{
    __shared__ float tile[34 * 34];
    __shared__ float wc[9];
    __shared__ float sscale, sshift;
    __shared__ double sm[256];
    const int tid = threadIdx.x;
    if (tid == 0) {
        const double n = 1048576.0;
        double m = sums[0] / n, v = sums[1] / n - (sums[0] / n) * (sums[0] / n);
        float sc = g[0] * (float)(1.0 / sqrt(v + 1e-5));
        sscale = sc; sshift = bb[0] - (float)m * sc;
    }
    if (tid < 9) wc[tid] = cw[tid];
    for (int i = tid; i < 34 * 34; i += 256) tile[i] = 0.f;
    __syncthreads();
    const float sc = sscale, sh = sshift;
    const long base = (long)blockIdx.x * 1024;
    for (int i = tid; i < 1024; i += 256) {
        int y = i >> 5, x = i & 31;
        tile[(y + 1) * 34 + (x + 1)] = fmaf(src[base + i], sc, sh);
    }
    __syncthreads();
    double s = 0, q = 0;
    for (int i = tid; i < 1024; i += 256) {
        int y = i >> 5, x = i & 31;
        const float* t0 = &tile[y * 34 + x];
        float o = t0[0] * wc[0] + t0[1] * wc[1] + t0[2] * wc[2]
                + t0[34] * wc[3] + t0[35] * wc[4] + t0[36] * wc[5]
                + t0[68] * wc[6] + t0[69] * wc[7] + t0[70] * wc[8];
        dst[base + i] = o;
        if (ACC) { s += o; q += (double)o * o; }
    }
    if (ACC) {
        double ts = blk_reduce(s, sm);
        double tq = blk_reduce(q, sm);
        if (tid == 0) { atomicAdd(&nextsums[0], ts); atomicAdd(&nextsums[1], tq); }
    }
}

// ========== elementwise relu(bn(x)) with stats accumulation for next bn ==========
__global__ __launch_bounds__(256) void relubn_k(
    const float* __restrict__ src, float* __restrict__ dst,
    const double* __restrict__ sums, const float* __restrict__ g, const float* __restrict__ bb,
    double* __restrict__ nextsums, int n)
{
    const double nn = (double)n;
    double m = sums[0] / nn, v = sums[1] / nn - (sums[0] / nn) * (sums[0] / nn);
    float sc = g[0] * (float)(1.0 / sqrt(v + 1e-5));
    float sh = bb[0] - (float)m * sc;
    double s = 0, q = 0;
    for (long i = (long)blockIdx.x * 256 + threadIdx.x; i < n; i += (long)gridDim.x * 256) {
        float x = fmaf(src[i], sc, sh);
        x = fmaxf(x, 0.f);
        dst[i] = x;
        s += x; q += (double)x * x;
    }
    __shared__ double sm[256];
    double ts = blk_reduce(s, sm);
    double tq = blk_reduce(q, sm);
    if (threadIdx.x == 0) { atomicAdd(&nextsums[0], ts); atomicAdd(&nextsums[1], tq); }
}

// ========== fully fused dual attention + aggregation + cos/bil/lin, one block per b ==========
__global__ __launch_bounds__(256) void attn_k(
    const float* __restrict__ pg1, const float* __restrict__ pg2,
    const float* __restrict__ qw, const float* __restrict__ qb,
    const float* __restrict__ kw, const float* __restrict__ kb,
    const float* __restrict__ vw, const float* __restrict__ vb,
    const float* __restrict__ lng, const float* __restrict__ lnb,
    const float* __restrict__ bilw, const float* __restrict__ lsw, const float* __restrict__ lsb,
    float* __restrict__ merged)
{
    __shared__ float P1[1024], P2[1024];
    __shared__ float Wq[1024], Wk[1024], Wv[1024];
    __shared__ float bq[32], bk[32], bv[32], sg[32], sb[32];
    __shared__ float rs1[32], rs2[32];
    __shared__ float Qm[1024], Km[32 * 33], Vm[1024];
    __shared__ float S[128 * 33];            // also reused for bilw (64x65 fits)
    __shared__ float O[32 * 33];
    __shared__ float mrow[32], irow[32];
    __shared__ float R1[64], R2[64];

    const int tid = threadIdx.x;
    const long pb = (long)blockIdx.x * 1024;
    for (int i = tid; i < 1024; i += 256) {
        P1[i] = pg1[pb + i]; P2[i] = pg2[pb + i];
        Wq[i] = qw[i]; Wk[i] = kw[i]; Wv[i] = vw[i];
    }
    if (tid < 32) { bq[tid] = qb[tid]; bk[tid] = kb[tid]; bv[tid] = vb[tid];
                    sg[tid] = lng[tid]; sb[tid] = lnb[tid]; }
    __syncthreads();
    if (tid < 64) {
        int s_ = tid & 31; bool two = tid >= 32;
        const float* P = two ? P2 : P1;
        float sum = 0;
        for (int f = 0; f < 32; f++) sum += P[s_ * 32 + f];
        float m = (sum != 0.f) ? 1.f : 0.f;
        if (two) rs2[s_] = m; else rs1[s_] = m;
    }
    __syncthreads();

    for (int pass = 0; pass < 2; pass++) {
        const float* Pq = pass ? P2 : P1;
        const float* Pk = pass ? P1 : P2;
        const float* qm = pass ? rs2 : rs1;
        const float* km = pass ? rs1 : rs2;
        for (int i = tid; i < 1024; i += 256) {
            int s_ = i >> 5, n = i & 31;
            float aq = bq[n], ak = bk[n], av = bv[n];
            for (int k = 0; k < 32; k++) {
                float pq = Pq[s_ * 32 + k], pk = Pk[s_ * 32 + k];
                aq = fmaf(pq, Wq[k * 32 + n], aq);
                ak = fmaf(pk, Wk[k * 32 + n], ak);
                av = fmaf(pq, Wv[k * 32 + n], av);
            }
            Qm[i] = fmaxf(aq, 0.f);
            Km[s_ * 33 + n] = fmaxf(ak, 0.f);
            Vm[i] = fmaxf(av, 0.f);
        }
        __syncthreads();
        for (int i = tid; i < 4096; i += 256) {
            int h = i >> 10, r = i & 1023, q = r >> 5, k = r & 31;
            float a = 0;
            for (int d = 0; d < 8; d++)
                a = fmaf(Qm[q * 32 + h * 8 + d], Km[k * 33 + h * 8 + d], a);
            a *= 0.35355339059327379f;
            if (km[k] == 0.f) a = NEGF;
            S[(h * 32 + q) * 33 + k] = a;
        }
        __syncthreads();
        if (tid < 128) {
            int base = tid * 33, q = tid & 31;
            float mx = -3.4e38f;
            for (int k = 0; k < 32; k++) mx = fmaxf(mx, S[base + k]);
            float sum = 0;
            for (int k = 0; k < 32; k++) sum += expf(S[base + k] - mx);
            float inv = qm[q] / sum;
            for (int k = 0; k < 32; k++) S[base + k] = expf(S[base + k] - mx) * inv;
        }
        __syncthreads();
        for (int i = tid; i < 1024; i += 256) {
            int s_ = i >> 5, f = i & 31, h = f >> 3;
            float a = 0;
            int sbase = (h * 32 + s_) * 33;
            for (int k = 0; k < 32; k++) a = fmaf(S[sbase + k], Vm[k * 32 + f], a);
            O[s_ * 33 + f] = a + Pq[i];
        }
        __syncthreads();
        if (tid < 32) {
            float m = 0;
            for (int f = 0; f < 32; f++) m += O[tid * 33 + f];
            m *= (1.f / 32.f);
            float v = 0;
            for (int f = 0; f < 32; f++) { float d = O[tid * 33 + f] - m; v += d * d; }
            v *= (1.f / 31.f);
            mrow[tid] = m;
            irow[tid] = 1.f / (sqrtf(v) + 1e-8f);
        }
        __syncthreads();
        for (int i = tid; i < 1024; i += 256) {
            int s_ = i >> 5, f = i & 31;
            float a = sg[f] * (O[s_ * 33 + f] - mrow[s_]) * irow[s_] + sb[f];
            O[s_ * 33 + f] = Pq[i] * a;
        }
        __syncthreads();
        float* R = pass ? R2 : R1;
        if (tid < 64) {
            int f = tid & 31;
            if (tid < 32) {
                float m = 0;
                for (int s_ = 0; s_ < 32; s_++) m += O[s_ * 33 + f];
                R[f] = m * (1.f / 32.f);
            } else {
                float mx = -3.4e38f;
                for (int s_ = 0; s_ < 32; s_++) mx = fmaxf(mx, O[s_ * 33 + f]);
                R[32 + f] = mx;
            }
        }
        __syncthreads();
    }
    for (int i = tid; i < 4096; i += 256) {
        int r = i >> 6, c = i & 63;
        S[r * 65 + c] = bilw[i];
    }
    __syncthreads();
    if (tid < 64) {
        float r1v = R1[tid], r2v = R2[tid];
        float dot = r1v * r2v, s1 = r1v * r1v, s2 = r2v * r2v;
        float u = 0;
        for (int j = 0; j < 64; j++) u = fmaf(S[tid * 65 + j], R2[j], u);
        float bilp = r1v * u;
        float linp = fmaf(r1v, lsw[tid], r2v * lsw[64 + tid]);
        for (int o = 32; o > 0; o >>= 1) {
            dot  += __shfl_down(dot, o);
            s1   += __shfl_down(s1, o);
            s2   += __shfl_down(s2, o);
            bilp += __shfl_down(bilp, o);
            linp += __shfl_down(linp, o);
        }
        const long mb = (long)blockIdx.x * MER;
        if (tid == 0) {
            float n1 = fmaxf(sqrtf(s1), 1e-8f), n2 = fmaxf(sqrtf(s2), 1e-8f);
            merged[mb + 2564] = dot / (n1 * n2);
            merged[mb + 2565] = bilp;
            merged[mb + 2566] = tanhf(linp + lsb[0]);
        }
        merged[mb + tid] = R1[tid];
        merged[mb + 64 + tid] = R2[tid];
    }
}

// ================= row norms =================
template<int SRC>
__global__ __launch_bounds__(256) void rownorm_k(const float* __restrict__ src,
                                                 float* __restrict__ outn, int ncols)
{
    const int b = blockIdx.x;
    double s = 0;
    for (int j = threadIdx.x; j < ncols; j += 256) {
        float v = (SRC == 1) ? src[(long)b * XROW + j + (j < PROT_ ? 0 : CC_)]
                             : src[(long)b * ncols + j];
        s += (double)v * v;
    }
    __shared__ double sm[256];
    double tot = blk_reduce(s, sm);
    if (threadIdx.x == 0) {
        float n = (float)sqrt(tot);
        outn[b] = (n == 0.f) ? 1.f : n;
    }
}

// ================= column stats (sum, sumsq) via f64 atomics =================
// 16 rows per y-block now (more parallelism)
template<int SRC>
__global__ __launch_bounds__(256) void colstats_k(
    const float* __restrict__ src, int ld, int ncols,
    const float* __restrict__ rownorm, double* __restrict__ stats)
{
    int col = blockIdx.x * 256 + threadIdx.x;
    if (col >= ncols) return;
    int r0 = blockIdx.y * 16;
    double s = 0, q = 0;
    for (int b = r0; b < r0 + 16; b++) {
        float v;
        if (SRC == 1)      v = src[(long)b * XROW + col + (col < PROT_ ? 0 : CC_)] / rownorm[b];
        else if (SRC == 2) v = src[(long)b * ld + col] / rownorm[b];
        else               v = src[(long)b * ld + col];
        s += v; q += (double)v * v;
    }
    atomicAdd(&stats[2 * col], s);
    atomicAdd(&stats[2 * col + 1], q);
}

// sonsen: standardize l2-normalized p columns into merged[:, 128 + j]
__global__ __launch_bounds__(256) void sonsen_k(
    const float* __restrict__ X, const float* __restrict__ pnorm,
    const double* __restrict__ stats, float* __restrict__ merged)
{
    int col = blockIdx.x * 256 + threadIdx.x;
    if (col >= SON) return;
    int b = blockIdx.y;
    float v = X[(long)b * XROW + col + (col < PROT_ ? 0 : CC_)] / pnorm[b];
    double m = stats[2 * col] * (1.0 / 1024.0);
    double var = stats[2 * col + 1] * (1.0 / 1024.0) - m * m;
    float sd = (float)sqrt(fmax(var, 0.0));
    if (sd == 0.f) sd = 1.f;
    merged[(long)b * MER + 128 + col] = (v - (float)m) / sd;
}

// merged: in-place l2row + column standardize
__global__ __launch_bounds__(256) void mtrans_k(
    float* __restrict__ mg, const float* __restrict__ mn, const double* __restrict__ st)
{
    int col = blockIdx.x * 256 + threadIdx.x;
    if (col >= MER) return;
    int b = blockIdx.y;
    double m = st[2 * col] * (1.0 / 1024.0);
    double var = st[2 * col + 1] * (1.0 / 1024.0) - m * m;
    float sd = (float)sqrt(fmax(var, 0.0));
    if (sd == 0.f) sd = 1.f;
    float v = mg[(long)b * MER + col] / mn[b];
    mg[(long)b * MER + col] = (v - (float)m) / sd;
}

// bn1d transform in place
__global__ __launch_bounds__(256) void bn1dtrans_k(
    float* __restrict__ h, int ncols, const double* __restrict__ st,
    const float* __restrict__ g, const float* __restrict__ bb)
{
    int col = blockIdx.x * 256 + threadIdx.x;
    if (col >= ncols) return;
    int b = blockIdx.y;
    double m = st[2 * col] / 1024.0;
    double var = st[2 * col + 1] / 1024.0 - m * m;
    float rs = (float)(1.0 / sqrt(var + 1e-5));
    float x = h[(long)b * ncols + col];
    h[(long)b * ncols + col] = (float)((double)x - m) * rs * g[col] + bb[col];
}

// L1 = 2*B*sum(emb^2) - 2*||sum_b emb||^2   (collapsed Gram)
__global__ __launch_bounds__(128) void l1_k(const float* __restrict__ emb, double* __restrict__ out)
{
    const int j = threadIdx.x;
    double s = 0, q = 0;
    for (int b = 0; b < 1024; b++) {
        float v = emb[b * 128 + j];
        s += v; q += (double)v * v;
    }
    __shared__ double sm[128];
    double qtot = blk_reduce(q, sm);
    double ssum = blk_reduce(s * s, sm);
    if (j == 0) out[0] = 2.0 * 1024.0 * qtot - 2.0 * ssum;
}

// final: bn1d over 2 cols + sigmoid + argmax + scalars
__global__ __launch_bounds__(1024) void final_k(
    const float* __restrict__ h4, const float* __restrict__ g2, const float* __restrict__ be2,
    const double* __restrict__ scal /* [0]=L2sum, [1]=L1 */, float* __restrict__ out)
{
    const int b = threadIdx.x;
    float x0 = h4[2 * b], x1 = h4[2 * b + 1];
    __shared__ double sm[1024];
    double red[4];
    double vals[4] = { (double)x0, (double)x0 * x0, (double)x1, (double)x1 * x1 };
    for (int p = 0; p < 4; p++) red[p] = blk_reduce(vals[p], sm);
    double m0 = red[0] / 1024.0, v0 = red[1] / 1024.0 - m0 * m0;
    double m1 = red[2] / 1024.0, v1 = red[3] / 1024.0 - m1 * m1;
    float r0 = (float)(1.0 / sqrt(v0 + 1e-5)), r1 = (float)(1.0 / sqrt(v1 + 1e-5));
    float y0 = (float)((double)x0 - m0) * r0 * g2[0] + be2[0];
    float y1 = (float)((double)x1 - m1) * r1 * g2[1] + be2[1];
    float p0 = 1.f / (1.f + expf(-y0));
    float p1 = 1.f / (1.f + expf(-y1));
    out[2 * b] = p0;
    out[2 * b + 1] = p1;
    out[2048 + b] = (p1 > p0) ? 1.f : 0.f;
    if (b == 0) {
        double L1 = scal[1], L2a = 0.1 * scal[0];
        out[3072] = (float)L1;
        out[3073] = (float)L2a;
        out[3074] = (float)(L1 + L2a);
    }
}

// ================================= host =================================
extern "C" void kernel_launch(void* const* d_in, const int* in_sizes, int n_in,
                              void* d_out, int out_size, void* d_ws, size_t ws_size,
                              hipStream_t stream)
{
    const float* X    = (const float*)d_in[0];
    const float* glw  = (const float*)d_in[1];
    const float* glb  = (const float*)d_in[2];
    const float* bnag = (const float*)d_in[3];
    const float* bnab = (const float*)d_in[4];
    const float* bn1g = (const float*)d_in[5];
    const float* bn1b = (const float*)d_in[6];
    const float* bnbg = (const float*)d_in[7];
    const float* bnbb = (const float*)d_in[8];
    const float* c1w  = (const float*)d_in[9];
    const float* c2w  = (const float*)d_in[10];
    const float* qw   = (const float*)d_in[11];
    const float* qb   = (const float*)d_in[12];
    const float* kw   = (const float*)d_in[13];
    const float* kb   = (const float*)d_in[14];
    const float* vw   = (const float*)d_in[15];
    const float* vb   = (const float*)d_in[16];
    const float* lng  = (const float*)d_in[17];
    const float* lnb  = (const float*)d_in[18];
    const float* bilw = (const float*)d_in[19];
    const float* lsw  = (const float*)d_in[20];
    const float* lsb  = (const float*)d_in[21];
    const float* e0w  = (const float*)d_in[22];
    const float* e0b  = (const float*)d_in[23];
    const float* e1w  = (const float*)d_in[24];
    const float* e1b  = (const float*)d_in[25];
    const float* d0w  = (const float*)d_in[26];
    const float* d0b  = (const float*)d_in[27];
    const float* d1w  = (const float*)d_in[28];
    const float* d1b  = (const float*)d_in[29];
    const float* cw1  = (const float*)d_in[30];
    const float* cb1  = (const float*)d_in[31];
    const float* cg1  = (const float*)d_in[32];
    const float* cbe1 = (const float*)d_in[33];
    const float* cw2  = (const float*)d_in[34];
    const float* cb2  = (const float*)d_in[35];
    const float* cw3  = (const float*)d_in[36];
    const float* cb3  = (const float*)d_in[37];
    const float* cw4  = (const float*)d_in[38];
    const float* cb4  = (const float*)d_in[39];
    const float* cg2  = (const float*)d_in[40];
    const float* cbe2 = (const float*)d_in[41];

    // ---- workspace layout ----
    double* dscr = (double*)d_ws;
    const size_t N_PST = 2 * (size_t)SON;   // 4872
    const size_t N_MST = 2 * (size_t)MER;   // 5134
    const size_t N_H1  = 2 * 512;           // 1024
    const size_t NDBL  = 14 + N_PST + N_MST + N_H1;
    double* bns  = dscr;          // [0..11] bn sums
    double* l2a  = dscr + 12;
    double* l1a  = dscr + 13;
    double* pst  = dscr + 14;
    double* mst  = pst + N_PST;
    double* h1st = mst + N_MST;
    float* f = (float*)(dscr + NDBL);
    float* bufA = f; f += 1048576;
    float* bufB = f; f += 1048576;
    float* pg1  = f; f += 1048576;
    float* pg2  = f; f += 1048576;
    float* emb  = f; f += 131072;
    float* mg   = f; f += (size_t)1024 * MER;
    float* h1   = f; f += 1024 * 512;
    float* h2   = f; f += 1024 * 256;
    float* h3   = f; f += 1024 * 128;
    float* h4   = f; f += 2048;
    float* pn   = f; f += 1024;
    float* mn   = f; f += 1024;
    float* t    = bufA;   // AE intermediates alias CNN staging buffers
    float* t2   = bufB;

    hipMemsetAsync(dscr, 0, NDBL * sizeof(double), stream);

    const dim3 blk(256);

    // ---- gated CNN chain, both sides (split-K GEMM: 1218 = 6*203) ----
    for (int s = 0; s < 2; s++) {
        const float* Xs = X + (long)s * XSIDE;
        double* s6 = bns + s * 6;
        float* pg = s ? pg2 : pg1;
        hipMemsetAsync(bufA, 0, 1048576 * sizeof(float), stream);
        gemm_sk<0><<<dim3(16, 16, 6), blk, 0, stream>>>(Xs, XROW, glw, bufA, 1024, 1024, PROT_, 203);
        bias_act_k<0><<<dim3(1024), blk, 0, stream>>>(bufA, glb, 1048576, 1024);
        meanvar_k<<<dim3(512), blk, 0, stream>>>(bufA, 1048576, s6 + 0);
        bnconv_k<1><<<dim3(1024), blk, 0, stream>>>(bufA, bufB, s6 + 0, bnag, bnab, c1w, s6 + 2);
        relubn_k<<<dim3(512), blk, 0, stream>>>(bufB, bufA, s6 + 2, bn1g, bn1b, s6 + 4, 1048576);
        bnconv_k<0><<<dim3(1024), blk, 0, stream>>>(bufA, pg, s6 + 4, bnbg, bnbb, c2w, nullptr);
    }

    // ---- attention block (r1, r2, cos, bil, lin into merged) ----
    attn_k<<<dim3(1024), blk, 0, stream>>>(pg1, pg2, qw, qb, kw, kb, vw, vb,
                                           lng, lnb, bilw, lsw, lsb, mg);

    // ---- sonsen into merged ----
    rownorm_k<1><<<dim3(1024), blk, 0, stream>>>(X, pn, SON);
    colstats_k<1><<<dim3(10, 64), blk, 0, stream>>>(X, 0, SON, pn, pst);
    sonsen_k<<<dim3(10, 1024), blk, 0, stream>>>(X, pn, pst, mg);

    // ---- merged: l2rows + scale (in place) ----
    rownorm_k<0><<<dim3(1024), blk, 0, stream>>>(mg, mn, MER);
    colstats_k<2><<<dim3(11, 64), blk, 0, stream>>>(mg, MER, MER, mn, mst);
    mtrans_k<<<dim3(11, 1024), blk, 0, stream>>>(mg, mn, mst);

    // ---- autoencoder (t, t2 alias bufA, bufB) ----
    hipMemsetAsync(t, 0, 1048576 * sizeof(float), stream);
    gemm_sk<1><<<dim3(16, 16, 8), blk, 0, stream>>>(X, 0, e0w, t, 1024, 1024, K2_, 2048);
    bias_act_k<2><<<dim3(1024), blk, 0, stream>>>(t, e0b, 1048576, 1024);

    hipMemsetAsync(emb, 0, 131072 * sizeof(float), stream);
    gemm_sk<0><<<dim3(2, 16, 8), blk, 0, stream>>>(t, 1024, e1w, emb, 1024, 128, 1024, 128);
    bias_act_k<2><<<dim3(128), blk, 0, stream>>>(emb, e1b, 131072, 128);

    l1_k<<<dim3(1), dim3(128), 0, stream>>>(emb, l1a);

    hipMemsetAsync(t2, 0, 1048576 * sizeof(float), stream);
    gemm_sk<0><<<dim3(16, 16, 4), blk, 0, stream>>>(emb, 128, d0w, t2, 1024, 1024, 128, 32);
    bias_act_k<2><<<dim3(1024), blk, 0, stream>>>(t2, d0b, 1048576, 1024);

    gemm_l2_k<<<dim3(256, 16), blk, 0, stream>>>(t2, d1w, d1b, X, l2a, 1024, K2_, 1024);

    // ---- classifier ----
    hipMemsetAsync(h1, 0, 524288 * sizeof(float), stream);
    gemm_sk<0><<<dim3(8, 16, 4), blk, 0, stream>>>(mg, MER, cw1, h1, 1024, 512, MER, 642);
    bias_act_k<0><<<dim3(512), blk, 0, stream>>>(h1, cb1, 524288, 512);
    colstats_k<0><<<dim3(2, 64), blk, 0, stream>>>(h1, 512, 512, nullptr, h1st);
    bn1dtrans_k<<<dim3(2, 1024), blk, 0, stream>>>(h1, 512, h1st, cg1, cbe1);

    hipMemsetAsync(h2, 0, 262144 * sizeof(float), stream);
    gemm_sk<0><<<dim3(4, 16, 4), blk, 0, stream>>>(h1, 512, cw2, h2, 1024, 256, 512, 128);
    bias_act_k<3><<<dim3(256), blk, 0, stream>>>(h2, cb2, 262144, 256);

    hipMemsetAsync(h3, 0, 131072 * sizeof(float), stream);
    gemm_sk<0><<<dim3(2, 16, 4), blk, 0, stream>>>(h2, 256, cw3, h3, 1024, 128, 256, 64);
    bias_act_k<0><<<dim3(128), blk, 0, stream>>>(h3, cb3, 131072, 128);

    gemm_k<0, 0><<<dim3(1, 16), blk, 0, stream>>>(h3, 128, cw4, cb4, h4, 1024, 2, 128);

    final_k<<<dim3(1), dim3(1024), 0, stream>>>(h4, cg2, cbe2, dscr + 12, (float*)d_out);
}

// Round 5
// 1493.545 us; speedup vs baseline: 4.0502x; 1.9257x over previous
//
#include <hip/hip_runtime.h>
#include <hip/hip_bf16.h>

// ---- problem constants ----
#define B_    1024
#define PROT_ 1218
#define CC_   8192
#define XSIDE 9410            // PROT + C
#define XROW  18820           // 2*(PROT+C)
#define MER   2567            // 2*64 + 2436 + 3
#define SON   2436            // 2*PROT
#define K2_   16384           // 2*C
#define NEGF  (-4294967295.0f)

using bf16x8 = __attribute__((ext_vector_type(8))) short;
using f32x4  = __attribute__((ext_vector_type(4))) float;

__device__ __forceinline__ unsigned short f2b(float f) {   // f32 -> bf16 RNE
    unsigned u = __float_as_uint(f);
    return (unsigned short)((u + 0x7FFF + ((u >> 16) & 1)) >> 16);
}

// ================= utility: block reduce (double) =================
__device__ __forceinline__ double blk_reduce(double v, double* sm) {
    int t = threadIdx.x;
    sm[t] = v; __syncthreads();
    for (int s = blockDim.x >> 1; s > 0; s >>= 1) {
        if (t < s) sm[t] += sm[t + s];
        __syncthreads();
    }
    double r = sm[0];
    __syncthreads();
    return r;
}

template<int ACT> __device__ __forceinline__ float apply_act(float v) {
    if (ACT == 1) return fmaxf(v, 0.f);
    if (ACT == 2) return (v >= 0.f) ? v : 0.01f * v;
    if (ACT == 3) return (v > 0.f) ? v : expm1f(v);
    return v;
}

// ======== conversions for the bf16 AE branch ========
// adj gather from X -> bf16 [1024][16384]
__global__ __launch_bounds__(256) void convadj_k(const float* __restrict__ X,
                                                 unsigned short* __restrict__ dst)
{
    int i = blockIdx.x * 256 + threadIdx.x;          // 2M threads, 8 elems each
    int row = i >> 11, c = (i & 2047) * 8;
    const float* src = X + (long)row * XROW + c + (c < CC_ ? PROT_ : SON);
    unsigned short o[8];
#pragma unroll
    for (int j = 0; j < 8; j++) o[j] = f2b(src[j]);
    *reinterpret_cast<uint4*>(dst + (long)row * 16384 + c) = *reinterpret_cast<uint4*>(o);
}

// plain f32 [M][K] (row stride lda) -> bf16 [M][Kp], zero pad K..Kp
__global__ __launch_bounds__(256) void conva_k(const float* __restrict__ src, int lda,
                                               int K, int Kp, unsigned short* __restrict__ dst)
{
    int i = blockIdx.x * 256 + threadIdx.x;          // M*Kp/8 threads
    int cpr = Kp >> 3;
    int row = i / cpr, c = (i % cpr) * 8;
    const float* s = src + (long)row * lda + c;
    unsigned short o[8];
#pragma unroll
    for (int j = 0; j < 8; j++) o[j] = (c + j < K) ? f2b(s[j]) : (unsigned short)0;
    *reinterpret_cast<uint4*>(dst + (long)row * Kp + c) = *reinterpret_cast<uint4*>(o);
}

// W f32 [K][N] -> Wt bf16 [N][Kp] (transposed), zero pad K..Kp. grid (Kp/64, N/64)
__global__ __launch_bounds__(256) void convw_k(const float* __restrict__ W,
                                               unsigned short* __restrict__ Wt,
                                               int K, int N, int Kp)
{
    __shared__ float tl[64][65];
    const int tid = threadIdx.x;
    int k0 = blockIdx.x * 64, n0 = blockIdx.y * 64;
#pragma unroll
    for (int i = 0; i < 16; i++) {
        int idx = tid + i * 256;
        int r = idx >> 6, c = idx & 63;
        int kg = k0 + r;
        tl[r][c] = (kg < K) ? W[(long)kg * N + n0 + c] : 0.f;
    }
    __syncthreads();
#pragma unroll
    for (int i = 0; i < 16; i++) {
        int idx = tid + i * 256;
        int r = idx >> 6, c = idx & 63;   // r = n index, c = k index
        Wt[(long)(n0 + r) * Kp + k0 + c] = f2b(tl[c][r]);
    }
}

// ======== bf16 MFMA GEMM, 128x128 tile, BK=64, 4 waves ========
// A bf16 [M][Kp], Bt bf16 [N][Kp]. MODE 0: atomicAdd into f32 C (split-K).
// MODE 1: fused L2 loss epilogue (recon never stored).
template<int MODE>
__global__ __launch_bounds__(256) void mfma_gemm_k(
    const unsigned short* __restrict__ A, const unsigned short* __restrict__ Bt,
    float* __restrict__ C, int M, int N, int Kp, int kc,
    const float* __restrict__ bias, const float* __restrict__ X,
    double* __restrict__ l2acc)
{
    __shared__ __align__(16) unsigned short Al[128 * 64];
    __shared__ __align__(16) unsigned short Bl[128 * 64];
    const int tid = threadIdx.x;
    const int wid = tid >> 6, lane = tid & 63;
    const int wr = wid >> 1, wc = wid & 1;
    const int lm = lane & 15, lk = lane >> 4;
    const int row0 = blockIdx.y * 128, col0 = blockIdx.x * 128;
    const int k0 = blockIdx.z * kc, kend = k0 + kc;

    f32x4 acc[4][4] = {};

    for (int kt = k0; kt < kend; kt += 64) {
#pragma unroll
        for (int i = 0; i < 4; i++) {
            int idx = tid + i * 256;          // 0..1023
            int r = idx >> 3, c8 = idx & 7;
            int off = (r * 128 + c8 * 16) ^ ((r & 7) << 4);
            uint4 va = *reinterpret_cast<const uint4*>(A + (long)(row0 + r) * Kp + kt + c8 * 8);
            *reinterpret_cast<uint4*>((char*)Al + off) = va;
            uint4 vb = *reinterpret_cast<const uint4*>(Bt + (long)(col0 + r) * Kp + kt + c8 * 8);
            *reinterpret_cast<uint4*>((char*)Bl + off) = vb;
        }
        __syncthreads();
#pragma unroll
        for (int kk = 0; kk < 64; kk += 32) {
            bf16x8 af[4], bfr[4];
#pragma unroll
            for (int mi = 0; mi < 4; mi++) {
                int r = wr * 64 + mi * 16 + lm;
                int off = (r * 128 + (kk + lk * 8) * 2) ^ ((r & 7) << 4);
                af[mi] = *reinterpret_cast<const bf16x8*>((const char*)Al + off);
            }
#pragma unroll
            for (int ni = 0; ni < 4; ni++) {
                int r = wc * 64 + ni * 16 + lm;
                int off = (r * 128 + (kk + lk * 8) * 2) ^ ((r & 7) << 4);
                bfr[ni] = *reinterpret_cast<const bf16x8*>((const char*)Bl + off);
            }
#pragma unroll
            for (int mi = 0; mi < 4; mi++)
#pragma unroll
                for (int ni = 0; ni < 4; ni++)
                    acc[mi][ni] = __builtin_amdgcn_mfma_f32_16x16x32_bf16(
                        af[mi], bfr[ni], acc[mi][ni], 0, 0, 0);
        }
        __syncthreads();
    }

    if (MODE == 0) {
#pragma unroll
        for (int mi = 0; mi < 4; mi++)
#pragma unroll
            for (int ni = 0; ni < 4; ni++)
#pragma unroll
                for (int r = 0; r < 4; r++) {
                    int grow = row0 + wr * 64 + mi * 16 + lk * 4 + r;
                    int gcol = col0 + wc * 64 + ni * 16 + lm;
                    atomicAdd(&C[(long)grow * N + gcol], acc[mi][ni][r]);
                }
    } else {
        double part = 0.0;
#pragma unroll
        for (int mi = 0; mi < 4; mi++)
#pragma unroll
            for (int ni = 0; ni < 4; ni++) {
                int gcol = col0 + wc * 64 + ni * 16 + lm;
                float bv = bias[gcol];
                long xoff = (long)gcol + (gcol < CC_ ? PROT_ : SON);
#pragma unroll
                for (int r = 0; r < 4; r++) {
                    int grow = row0 + wr * 64 + mi * 16 + lk * 4 + r;
                    float recon = acc[mi][ni][r] + bv;
                    recon = (recon >= 0.f) ? recon : 0.01f * recon;
                    float adj = X[(long)grow * XROW + xoff];
                    float d = (adj - recon) * ((adj != 0.f) ? 5.f : 1.f);
                    part += (double)d * (double)d;
                }
            }
        double* smd = (double*)Al;     // reuse LDS (post-barrier)
        double tot = blk_reduce(part, smd);
        if (tid == 0) atomicAdd(l2acc, tot);
    }
}

// ================= split-K tiled f32 GEMM (partials via atomicAdd) =================
template<int AG>
__global__ __launch_bounds__(256) void gemm_sk(
    const float* __restrict__ A, int lda,
    const float* __restrict__ W,
    float* __restrict__ C, int M, int N, int K, int kc)
{
    __shared__ float As[16][65];
    __shared__ float Ws[16][65];
    const int tid = threadIdx.x;
    const int tx = tid & 15, ty = tid >> 4;
    const int row0 = blockIdx.y * 64, col0 = blockIdx.x * 64;
    const int k0 = blockIdx.z * kc;
    const int kend = min(K, k0 + kc);
    float acc[4][4] = {};
    for (int kt = k0; kt < kend; kt += 16) {
#pragma unroll
        for (int i = 0; i < 4; i++) {
            int idx = tid + i * 256;
            int m = idx >> 4, kk = idx & 15;
            int kg = kt + kk;
            float v = 0.f;
            if (kg < kend) {
                if (AG == 0) v = A[(long)(row0 + m) * lda + kg];
                else         v = A[(long)(row0 + m) * XROW + kg + (kg < CC_ ? PROT_ : SON)];
            }
            As[kk][m] = v;
        }
#pragma unroll
        for (int i = 0; i < 4; i++) {
            int idx = tid + i * 256;
            int n = idx & 63, kk = idx >> 6;
            int kg = kt + kk, cg = col0 + n;
            float v = 0.f;
            if (kg < kend && cg < N) v = W[(long)kg * N + cg];
            Ws[kk][n] = v;
        }
        __syncthreads();
#pragma unroll
        for (int kk = 0; kk < 16; kk++) {
            float a[4], w[4];
#pragma unroll
            for (int i = 0; i < 4; i++) a[i] = As[kk][ty * 4 + i];
#pragma unroll
            for (int j = 0; j < 4; j++) w[j] = Ws[kk][tx * 4 + j];
#pragma unroll
            for (int i = 0; i < 4; i++)
#pragma unroll
                for (int j = 0; j < 4; j++)
                    acc[i][j] = fmaf(a[i], w[j], acc[i][j]);
        }
        __syncthreads();
    }
#pragma unroll
    for (int i = 0; i < 4; i++) {
        int r = row0 + ty * 4 + i;
#pragma unroll
        for (int j = 0; j < 4; j++) {
            int c = col0 + tx * 4 + j;
            if (c < N) atomicAdd(&C[(long)r * N + c], acc[i][j]);
        }
    }
}

// epilogue: C = act(C + bias), vectorized float4 (N multiple of 4)
template<int ACT>
__global__ __launch_bounds__(256) void bias_act_k(float* __restrict__ C,
        const float* __restrict__ bias, int MN, int N)
{
    int i = (blockIdx.x * 256 + threadIdx.x) * 4;
    if (i >= MN) return;
    float4 v = *reinterpret_cast<float4*>(&C[i]);
    int c = i % N;
    v.x = apply_act<ACT>(v.x + bias[c]);
    v.y = apply_act<ACT>(v.y + bias[c + 1]);
    v.z = apply_act<ACT>(v.z + bias[c + 2]);
    v.w = apply_act<ACT>(v.w + bias[c + 3]);
    *reinterpret_cast<float4*>(&C[i]) = v;
}

// ================= generic tiled f32 GEMM (kept for tiny cw4) =================
template<int ACT, int AG>
__global__ __launch_bounds__(256) void gemm_k(
    const float* __restrict__ A, int lda,
    const float* __restrict__ W, const float* __restrict__ bias,
    float* __restrict__ C, int M, int N, int K)
{
    __shared__ float As[16][65];
    __shared__ float Ws[16][65];
    const int tid = threadIdx.x;
    const int tx = tid & 15, ty = tid >> 4;
    const int row0 = blockIdx.y * 64, col0 = blockIdx.x * 64;
    float acc[4][4] = {};
    for (int kt = 0; kt < K; kt += 16) {
#pragma unroll
        for (int i = 0; i < 4; i++) {
            int idx = tid + i * 256;
            int m = idx >> 4, kk = idx & 15;
            int kg = kt + kk;
            float v = 0.f;
            if (kg < K) {
                if (AG == 0) v = A[(long)(row0 + m) * lda + kg];
                else         v = A[(long)(row0 + m) * XROW + kg + (kg < CC_ ? PROT_ : SON)];
            }
            As[kk][m] = v;
        }
#pragma unroll
        for (int i = 0; i < 4; i++) {
            int idx = tid + i * 256;
            int n = idx & 63, kk = idx >> 6;
            int kg = kt + kk, cg = col0 + n;
            float v = 0.f;
            if (kg < K && cg < N) v = W[(long)kg * N + cg];
            Ws[kk][n] = v;
        }
        __syncthreads();
#pragma unroll
        for (int kk = 0; kk < 16; kk++) {
            float a[4], w[4];
#pragma unroll
            for (int i = 0; i < 4; i++) a[i] = As[kk][ty * 4 + i];
#pragma unroll
            for (int j = 0; j < 4; j++) w[j] = Ws[kk][tx * 4 + j];
#pragma unroll
            for (int i = 0; i < 4; i++)
#pragma unroll
                for (int j = 0; j < 4; j++)
                    acc[i][j] = fmaf(a[i], w[j], acc[i][j]);
        }
        __syncthreads();
    }
#pragma unroll
    for (int i = 0; i < 4; i++) {
        int r = row0 + ty * 4 + i;
#pragma unroll
        for (int j = 0; j < 4; j++) {
            int c = col0 + tx * 4 + j;
            if (c < N) {
                float v = acc[i][j] + (bias ? bias[c] : 0.f);
                if (ACT == 1)      v = fmaxf(v, 0.f);
                else if (ACT == 2) v = (v >= 0.f) ? v : 0.01f * v;
                else if (ACT == 3) v = (v > 0.f) ? v : expm1f(v);
                C[(long)r * N + c] = v;
            }
        }
    }
}

// ================= mean/var reduction over a buffer =================
__global__ __launch_bounds__(256) void meanvar_k(const float* __restrict__ src, int n,
                                                 double* __restrict__ out2)
{
    double s = 0, q = 0;
    for (long i = (long)blockIdx.x * 256 + threadIdx.x; i < n; i += (long)gridDim.x * 256) {
        float v = src[i]; s += v; q += (double)v * v;
    }
    __shared__ double sm[256];
    double ts = blk_reduce(s, sm);
    double tq = blk_reduce(q, sm);
    if (threadIdx.x == 0) { atomicAdd(&out2[0], ts); atomicAdd(&out2[1], tq); }
}

// ========== bn2d (scalar affine from sums) + 3x3 SAME conv, per-image block ==========
template<int ACC>
__global__ __launch_bounds__(256) void bnconv_k(
    const float* __restrict__ src, float* __restrict__ dst,
    const double* __restrict__ sums, const float* __restrict__ g, const float* __restrict__ bb,
    const float* __restrict__ cw, double* __restrict__ nextsums)
{
    __shared__ float tile[34 * 34];
    __shared__ float wc[9];
    __shared__ float sscale, sshift;
    __shared__ double sm[256];
    const int tid = threadIdx.x;
    if (tid == 0) {
        const double n = 1048576.0;
        double m = sums[0] / n, v = sums[1] / n - (sums[0] / n) * (sums[0] / n);
        float sc = g[0] * (float)(1.0 / sqrt(v + 1e-5));
        sscale = sc; sshift = bb[0] - (float)m * sc;
    }
    if (tid < 9) wc[tid] = cw[tid];
    for (int i = tid; i < 34 * 34; i += 256) tile[i] = 0.f;
    __syncthreads();
    const float sc = sscale, sh = sshift;
    const long base = (long)blockIdx.x * 1024;
    for (int i = tid; i < 1024; i += 256) {
        int y = i >> 5, x = i & 31;
        tile[(y + 1) * 34 + (x + 1)] = fmaf(src[base + i], sc, sh);
    }
    __syncthreads();
    double s = 0, q = 0;
    for (int i = tid; i < 1024; i += 256) {
        int y = i >> 5, x = i & 31;
        const float* t0 = &tile[y * 34 + x];
        float o = t0[0] * wc[0] + t0[1] * wc[1] + t0[2] * wc[2]
                + t0[34] * wc[3] + t0[35] * wc[4] + t0[36] * wc[5]
                + t0[68] * wc[6] + t0[69] * wc[7] + t0[70] * wc[8];
        dst[base + i] = o;
        if (ACC) { s += o; q += (double)o * o; }
    }
    if (ACC) {
        double ts = blk_reduce(s, sm);
        double tq = blk_reduce(q, sm);
        if (tid == 0) { atomicAdd(&nextsums[0], ts); atomicAdd(&nextsums[1], tq); }
    }
}

// ========== elementwise relu(bn(x)) with stats accumulation for next bn ==========
__global__ __launch_bounds__(256) void relubn_k(
    const float* __restrict__ src, float* __restrict__ dst,
    const double* __restrict__ sums, const float* __restrict__ g, const float* __restrict__ bb,
    double* __restrict__ nextsums, int n)
{
    const double nn = (double)n;
    double m = sums[0] / nn, v = sums[1] / nn - (sums[0] / nn) * (sums[0] / nn);
    float sc = g[0] * (float)(1.0 / sqrt(v + 1e-5));
    float sh = bb[0] - (float)m * sc;
    double s = 0, q = 0;
    for (long i = (long)blockIdx.x * 256 + threadIdx.x; i < n; i += (long)gridDim.x * 256) {
        float x = fmaf(src[i], sc, sh);
        x = fmaxf(x, 0.f);
        dst[i] = x;
        s += x; q += (double)x * x;
    }
    __shared__ double sm[256];
    double ts = blk_reduce(s, sm);
    double tq = blk_reduce(q, sm);
    if (threadIdx.x == 0) { atomicAdd(&nextsums[0], ts); atomicAdd(&nextsums[1], tq); }
}

// ========== fully fused dual attention + aggregation + cos/bil/lin, one block per b ==========
__global__ __launch_bounds__(256) void attn_k(
    const float* __restrict__ pg1, const float* __restrict__ pg2,
    const float* __restrict__ qw, const float* __restrict__ qb,
    const float* __restrict__ kw, const float* __restrict__ kb,
    const float* __restrict__ vw, const float* __restrict__ vb,
    const float* __restrict__ lng, const float* __restrict__ lnb,
    const float* __restrict__ bilw, const float* __restrict__ lsw, const float* __restrict__ lsb,
    float* __restrict__ merged)
{
    __shared__ float P1[1024], P2[1024];
    __shared__ float Wq[1024], Wk[1024], Wv[1024];
    __shared__ float bq[32], bk[32], bv[32], sg[32], sb[32];
    __shared__ float rs1[32], rs2[32];
    __shared__ float Qm[1024], Km[32 * 33], Vm[1024];
    __shared__ float S[128 * 33];
    __shared__ float O[32 * 33];
    __shared__ float mrow[32], irow[32];
    __shared__ float R1[64], R2[64];

    const int tid = threadIdx.x;
    const long pb = (long)blockIdx.x * 1024;
    for (int i = tid; i < 1024; i += 256) {
        P1[i] = pg1[pb + i]; P2[i] = pg2[pb + i];
        Wq[i] = qw[i]; Wk[i] = kw[i]; Wv[i] = vw[i];
    }
    if (tid < 32) { bq[tid] = qb[tid]; bk[tid] = kb[tid]; bv[tid] = vb[tid];
                    sg[tid] = lng[tid]; sb[tid] = lnb[tid]; }
    __syncthreads();
    if (tid < 64) {
        int s_ = tid & 31; bool two = tid >= 32;
        const float* P = two ? P2 : P1;
        float sum = 0;
        for (int f = 0; f < 32; f++) sum += P[s_ * 32 + f];
        float m = (sum != 0.f) ? 1.f : 0.f;
        if (two) rs2[s_] = m; else rs1[s_] = m;
    }
    __syncthreads();

    for (int pass = 0; pass < 2; pass++) {
        const float* Pq = pass ? P2 : P1;
        const float* Pk = pass ? P1 : P2;
        const float* qm = pass ? rs2 : rs1;
        const float* km = pass ? rs1 : rs2;
        for (int i = tid; i < 1024; i += 256) {
            int s_ = i >> 5, n = i & 31;
            float aq = bq[n], ak = bk[n], av = bv[n];
            for (int k = 0; k < 32; k++) {
                float pq = Pq[s_ * 32 + k], pk = Pk[s_ * 32 + k];
                aq = fmaf(pq, Wq[k * 32 + n], aq);
                ak = fmaf(pk, Wk[k * 32 + n], ak);
                av = fmaf(pq, Wv[k * 32 + n], av);
            }
            Qm[i] = fmaxf(aq, 0.f);
            Km[s_ * 33 + n] = fmaxf(ak, 0.f);
            Vm[i] = fmaxf(av, 0.f);
        }
        __syncthreads();
        for (int i = tid; i < 4096; i += 256) {
            int h = i >> 10, r = i & 1023, q = r >> 5, k = r & 31;
            float a = 0;
            for (int d = 0; d < 8; d++)
                a = fmaf(Qm[q * 32 + h * 8 + d], Km[k * 33 + h * 8 + d], a);
            a *= 0.35355339059327379f;
            if (km[k] == 0.f) a = NEGF;
            S[(h * 32 + q) * 33 + k] = a;
        }
        __syncthreads();
        if (tid < 128) {
            int base = tid * 33, q = tid & 31;
            float mx = -3.4e38f;
            for (int k = 0; k < 32; k++) mx = fmaxf(mx, S[base + k]);
            float sum = 0;
            for (int k = 0; k < 32; k++) sum += expf(S[base + k] - mx);
            float inv = qm[q] / sum;
            for (int k = 0; k < 32; k++) S[base + k] = expf(S[base + k] - mx) * inv;
        }
        __syncthreads();
        for (int i = tid; i < 1024; i += 256) {
            int s_ = i >> 5, f = i & 31, h = f >> 3;
            float a = 0;
            int sbase = (h * 32 + s_) * 33;
            for (int k = 0; k < 32; k++) a = fmaf(S[sbase + k], Vm[k * 32 + f], a);
            O[s_ * 33 + f] = a + Pq[i];
        }
        __syncthreads();
        if (tid < 32) {
            float m = 0;
            for (int f = 0; f < 32; f++) m += O[tid * 33 + f];
            m *= (1.f / 32.f);
            float v = 0;
            for (int f = 0; f < 32; f++) { float d = O[tid * 33 + f] - m; v += d * d; }
            v *= (1.f / 31.f);
            mrow[tid] = m;
            irow[tid] = 1.f / (sqrtf(v) + 1e-8f);
        }
        __syncthreads();
        for (int i = tid; i < 1024; i += 256) {
            int s_ = i >> 5, f = i & 31;
            float a = sg[f] * (O[s_ * 33 + f] - mrow[s_]) * irow[s_] + sb[f];
            O[s_ * 33 + f] = Pq[i] * a;
        }
        __syncthreads();
        float* R = pass ? R2 : R1;
        if (tid < 64) {
            int f = tid & 31;
            if (tid < 32) {
                float m = 0;
                for (int s_ = 0; s_ < 32; s_++) m += O[s_ * 33 + f];
                R[f] = m * (1.f / 32.f);
            } else {
                float mx = -3.4e38f;
                for (int s_ = 0; s_ < 32; s_++) mx = fmaxf(mx, O[s_ * 33 + f]);
                R[32 + f] = mx;
            }
        }
        __syncthreads();
    }
    for (int i = tid; i < 4096; i += 256) {
        int r = i >> 6, c = i & 63;
        S[r * 65 + c] = bilw[i];
    }
    __syncthreads();
    if (tid < 64) {
        float r1v = R1[tid], r2v = R2[tid];
        float dot = r1v * r2v, s1 = r1v * r1v, s2 = r2v * r2v;
        float u = 0;
        for (int j = 0; j < 64; j++) u = fmaf(S[tid * 65 + j], R2[j], u);
        float bilp = r1v * u;
        float linp = fmaf(r1v, lsw[tid], r2v * lsw[64 + tid]);
        for (int o = 32; o > 0; o >>= 1) {
            dot  += __shfl_down(dot, o);
            s1   += __shfl_down(s1, o);
            s2   += __shfl_down(s2, o);
            bilp += __shfl_down(bilp, o);
            linp += __shfl_down(linp, o);
        }
        const long mb = (long)blockIdx.x * MER;
        if (tid == 0) {
            float n1 = fmaxf(sqrtf(s1), 1e-8f), n2 = fmaxf(sqrtf(s2), 1e-8f);
            merged[mb + 2564] = dot / (n1 * n2);
            merged[mb + 2565] = bilp;
            merged[mb + 2566] = tanhf(linp + lsb[0]);
        }
        merged[mb + tid] = R1[tid];
        merged[mb + 64 + tid] = R2[tid];
    }
}

// ================= row norms =================
template<int SRC>
__global__ __launch_bounds__(256) void rownorm_k(const float* __restrict__ src,
                                                 float* __restrict__ outn, int ncols)
{
    const int b = blockIdx.x;
    double s = 0;
    for (int j = threadIdx.x; j < ncols; j += 256) {
        float v = (SRC == 1) ? src[(long)b * XROW + j + (j < PROT_ ? 0 : CC_)]
                             : src[(long)b * ncols + j];
        s += (double)v * v;
    }
    __shared__ double sm[256];
    double tot = blk_reduce(s, sm);
    if (threadIdx.x == 0) {
        float n = (float)sqrt(tot);
        outn[b] = (n == 0.f) ? 1.f : n;
    }
}

// ================= column stats (sum, sumsq) via f64 atomics =================
template<int SRC>
__global__ __launch_bounds__(256) void colstats_k(
    const float* __restrict__ src, int ld, int ncols,
    const float* __restrict__ rownorm, double* __restrict__ stats)
{
    int col = blockIdx.x * 256 + threadIdx.x;
    if (col >= ncols) return;
    int r0 = blockIdx.y * 16;
    double s = 0, q = 0;
    for (int b = r0; b < r0 + 16; b++) {
        float v;
        if (SRC == 1)      v = src[(long)b * XROW + col + (col < PROT_ ? 0 : CC_)] / rownorm[b];
        else if (SRC == 2) v = src[(long)b * ld + col] / rownorm[b];
        else               v = src[(long)b * ld + col];
        s += v; q += (double)v * v;
    }
    atomicAdd(&stats[2 * col], s);
    atomicAdd(&stats[2 * col + 1], q);
}

// sonsen: standardize l2-normalized p columns into merged[:, 128 + j]
__global__ __launch_bounds__(256) void sonsen_k(
    const float* __restrict__ X, const float* __restrict__ pnorm,
    const double* __restrict__ stats, float* __restrict__ merged)
{
    int col = blockIdx.x * 256 + threadIdx.x;
    if (col >= SON) return;
    int b = blockIdx.y;
    float v = X[(long)b * XROW + col + (col < PROT_ ? 0 : CC_)] / pnorm[b];
    double m = stats[2 * col] * (1.0 / 1024.0);
    double var = stats[2 * col + 1] * (1.0 / 1024.0) - m * m;
    float sd = (float)sqrt(fmax(var, 0.0));
    if (sd == 0.f) sd = 1.f;
    merged[(long)b * MER + 128 + col] = (v - (float)m) / sd;
}

// merged: in-place l2row + column standardize
__global__ __launch_bounds__(256) void mtrans_k(
    float* __restrict__ mg, const float* __restrict__ mn, const double* __restrict__ st)
{
    int col = blockIdx.x * 256 + threadIdx.x;
    if (col >= MER) return;
    int b = blockIdx.y;
    double m = st[2 * col] * (1.0 / 1024.0);
    double var = st[2 * col + 1] * (1.0 / 1024.0) - m * m;
    float sd = (float)sqrt(fmax(var, 0.0));
    if (sd == 0.f) sd = 1.f;
    float v = mg[(long)b * MER + col] / mn[b];
    mg[(long)b * MER + col] = (v - (float)m) / sd;
}

// bn1d transform in place
__global__ __launch_bounds__(256) void bn1dtrans_k(
    float* __restrict__ h, int ncols, const double* __restrict__ st,
    const float* __restrict__ g, const float* __restrict__ bb)
{
    int col = blockIdx.x * 256 + threadIdx.x;
    if (col >= ncols) return;
    int b = blockIdx.y;
    double m = st[2 * col] / 1024.0;
    double var = st[2 * col + 1] / 1024.0 - m * m;
    float rs = (float)(1.0 / sqrt(var + 1e-5));
    float x = h[(long)b * ncols + col];
    h[(long)b * ncols + col] = (float)((double)x - m) * rs * g[col] + bb[col];
}

// L1 = 2*B*sum(emb^2) - 2*||sum_b emb||^2   (collapsed Gram)
__global__ __launch_bounds__(128) void l1_k(const float* __restrict__ emb, double* __restrict__ out)
{
    const int j = threadIdx.x;
    double s = 0, q = 0;
    for (int b = 0; b < 1024; b++) {
        float v = emb[b * 128 + j];
        s += v; q += (double)v * v;
    }
    __shared__ double sm[128];
    double qtot = blk_reduce(q, sm);
    double ssum = blk_reduce(s * s, sm);
    if (j == 0) out[0] = 2.0 * 1024.0 * qtot - 2.0 * ssum;
}

// final: bn1d over 2 cols + sigmoid + argmax + scalars
__global__ __launch_bounds__(1024) void final_k(
    const float* __restrict__ h4, const float* __restrict__ g2, const float* __restrict__ be2,
    const double* __restrict__ scal /* [0]=L2sum, [1]=L1 */, float* __restrict__ out)
{
    const int b = threadIdx.x;
    float x0 = h4[2 * b], x1 = h4[2 * b + 1];
    __shared__ double sm[1024];
    double red[4];
    double vals[4] = { (double)x0, (double)x0 * x0, (double)x1, (double)x1 * x1 };
    for (int p = 0; p < 4; p++) red[p] = blk_reduce(vals[p], sm);
    double m0 = red[0] / 1024.0, v0 = red[1] / 1024.0 - m0 * m0;
    double m1 = red[2] / 1024.0, v1 = red[3] / 1024.0 - m1 * m1;
    float r0 = (float)(1.0 / sqrt(v0 + 1e-5)), r1 = (float)(1.0 / sqrt(v1 + 1e-5));
    float y0 = (float)((double)x0 - m0) * r0 * g2[0] + be2[0];
    float y1 = (float)((double)x1 - m1) * r1 * g2[1] + be2[1];
    float p0 = 1.f / (1.f + expf(-y0));
    float p1 = 1.f / (1.f + expf(-y1));
    out[2 * b] = p0;
    out[2 * b + 1] = p1;
    out[2048 + b] = (p1 > p0) ? 1.f : 0.f;
    if (b == 0) {
        double L1 = scal[1], L2a = 0.1 * scal[0];
        out[3072] = (float)L1;
        out[3073] = (float)L2a;
        out[3074] = (float)(L1 + L2a);
    }
}

// ================================= host =================================
extern "C" void kernel_launch(void* const* d_in, const int* in_sizes, int n_in,
                              void* d_out, int out_size, void* d_ws, size_t ws_size,
                              hipStream_t stream)
{
    const float* X    = (const float*)d_in[0];
    const float* glw  = (const float*)d_in[1];
    const float* glb  = (const float*)d_in[2];
    const float* bnag = (const float*)d_in[3];
    const float* bnab = (const float*)d_in[4];
    const float* bn1g = (const float*)d_in[5];
    const float* bn1b = (const float*)d_in[6];
    const float* bnbg = (const float*)d_in[7];
    const float* bnbb = (const float*)d_in[8];
    const float* c1w  = (const float*)d_in[9];
    const float* c2w  = (const float*)d_in[10];
    const float* qw   = (const float*)d_in[11];
    const float* qb   = (const float*)d_in[12];
    const float* kw   = (const float*)d_in[13];
    const float* kb   = (const float*)d_in[14];
    const float* vw   = (const float*)d_in[15];
    const float* vb   = (const float*)d_in[16];
    const float* lng  = (const float*)d_in[17];
    const float* lnb  = (const float*)d_in[18];
    const float* bilw = (const float*)d_in[19];
    const float* lsw  = (const float*)d_in[20];
    const float* lsb  = (const float*)d_in[21];
    const float* e0w  = (const float*)d_in[22];
    const float* e0b  = (const float*)d_in[23];
    const float* e1w  = (const float*)d_in[24];
    const float* e1b  = (const float*)d_in[25];
    const float* d0w  = (const float*)d_in[26];
    const float* d0b  = (const float*)d_in[27];
    const float* d1w  = (const float*)d_in[28];
    const float* d1b  = (const float*)d_in[29];
    const float* cw1  = (const float*)d_in[30];
    const float* cb1  = (const float*)d_in[31];
    const float* cg1  = (const float*)d_in[32];
    const float* cbe1 = (const float*)d_in[33];
    const float* cw2  = (const float*)d_in[34];
    const float* cb2  = (const float*)d_in[35];
    const float* cw3  = (const float*)d_in[36];
    const float* cb3  = (const float*)d_in[37];
    const float* cw4  = (const float*)d_in[38];
    const float* cb4  = (const float*)d_in[39];
    const float* cg2  = (const float*)d_in[40];
    const float* cbe2 = (const float*)d_in[41];

    // ---- workspace layout ----
    double* dscr = (double*)d_ws;
    const size_t N_PST = 2 * (size_t)SON;
    const size_t N_MST = 2 * (size_t)MER;
    const size_t N_H1  = 2 * 512;
    const size_t NDBL  = 14 + N_PST + N_MST + N_H1;
    double* bns  = dscr;
    double* l2a  = dscr + 12;
    double* l1a  = dscr + 13;
    double* pst  = dscr + 14;
    double* mst  = pst + N_PST;
    double* h1st = mst + N_MST;
    float* f = (float*)(dscr + NDBL);
    float* bufA = f; f += 1048576;
    float* bufB = f; f += 1048576;
    float* pg1  = f; f += 1048576;
    float* pg2  = f; f += 1048576;
    float* emb  = f; f += 131072;
    float* mg   = f; f += (size_t)1024 * MER;
    float* h1   = f; f += 1024 * 512;
    float* h2   = f; f += 1024 * 256;
    float* h3   = f; f += 1024 * 128;
    float* h4   = f; f += 2048;
    float* pn   = f; f += 1024;
    float* mn   = f; f += 1024;
    f += 1024;                         // pad to keep 16B alignment downstream
    unsigned short* adjb = (unsigned short*)f;           // 1024x16384 bf16 (32MB)
    unsigned short* wt   = adjb + (size_t)1024 * 16384;  // 16384x1024 / 1024x16384 bf16 (32MB, reused)
    unsigned short* t2b  = adjb;                         // 1024x1024 bf16, reuses adjb (dead by then)
    float* t    = bufA;   // AE intermediates alias CNN staging buffers
    float* t2   = bufB;

    hipMemsetAsync(dscr, 0, NDBL * sizeof(double), stream);

    const dim3 blk(256);

    // ---- gated CNN chain, both sides (f32: feeds pred path, keep exact) ----
    for (int s = 0; s < 2; s++) {
        const float* Xs = X + (long)s * XSIDE;
        double* s6 = bns + s * 6;
        float* pg = s ? pg2 : pg1;
        hipMemsetAsync(bufA, 0, 1048576 * sizeof(float), stream);
        gemm_sk<0><<<dim3(16, 16, 6), blk, 0, stream>>>(Xs, XROW, glw, bufA, 1024, 1024, PROT_, 203);
        bias_act_k<0><<<dim3(1024), blk, 0, stream>>>(bufA, glb, 1048576, 1024);
        meanvar_k<<<dim3(512), blk, 0, stream>>>(bufA, 1048576, s6 + 0);
        bnconv_k<1><<<dim3(1024), blk, 0, stream>>>(bufA, bufB, s6 + 0, bnag, bnab, c1w, s6 + 2);
        relubn_k<<<dim3(512), blk, 0, stream>>>(bufB, bufA, s6 + 2, bn1g, bn1b, s6 + 4, 1048576);
        bnconv_k<0><<<dim3(1024), blk, 0, stream>>>(bufA, pg, s6 + 4, bnbg, bnbb, c2w, nullptr);
    }

    // ---- attention block ----
    attn_k<<<dim3(1024), blk, 0, stream>>>(pg1, pg2, qw, qb, kw, kb, vw, vb,
                                           lng, lnb, bilw, lsw, lsb, mg);

    // ---- sonsen into merged ----
    rownorm_k<1><<<dim3(1024), blk, 0, stream>>>(X, pn, SON);
    colstats_k<1><<<dim3(10, 64), blk, 0, stream>>>(X, 0, SON, pn, pst);
    sonsen_k<<<dim3(10, 1024), blk, 0, stream>>>(X, pn, pst, mg);

    // ---- merged: l2rows + scale ----
    rownorm_k<0><<<dim3(1024), blk, 0, stream>>>(mg, mn, MER);
    colstats_k<2><<<dim3(11, 64), blk, 0, stream>>>(mg, MER, MER, mn, mst);
    mtrans_k<<<dim3(11, 1024), blk, 0, stream>>>(mg, mn, mst);

    // ---- autoencoder: bf16 MFMA branch (feeds only L1/L2 losses) ----
    convw_k<<<dim3(256, 16), blk, 0, stream>>>(e0w, wt, K2_, 1024, K2_);       // e0w -> Wt[1024][16384]
    convadj_k<<<dim3(8192), blk, 0, stream>>>(X, adjb);                        // adj -> bf16
    hipMemsetAsync(t, 0, 1048576 * sizeof(float), stream);
    mfma_gemm_k<0><<<dim3(8, 8, 4), blk, 0, stream>>>(adjb, wt, t, 1024, 1024, K2_, 4096,
                                                      nullptr, nullptr, nullptr);
    bias_act_k<2><<<dim3(1024), blk, 0, stream>>>(t, e0b, 1048576, 1024);

    hipMemsetAsync(emb, 0, 131072 * sizeof(float), stream);
    gemm_sk<0><<<dim3(2, 16, 8), blk, 0, stream>>>(t, 1024, e1w, emb, 1024, 128, 1024, 128);
    bias_act_k<2><<<dim3(128), blk, 0, stream>>>(emb, e1b, 131072, 128);

    l1_k<<<dim3(1), dim3(128), 0, stream>>>(emb, l1a);

    hipMemsetAsync(t2, 0, 1048576 * sizeof(float), stream);
    gemm_sk<0><<<dim3(16, 16, 4), blk, 0, stream>>>(emb, 128, d0w, t2, 1024, 1024, 128, 32);
    bias_act_k<2><<<dim3(1024), blk, 0, stream>>>(t2, d0b, 1048576, 1024);

    conva_k<<<dim3(512), blk, 0, stream>>>(t2, 1024, 1024, 1024, t2b);         // t2 -> bf16 (reuses adjb)
    convw_k<<<dim3(16, 256), blk, 0, stream>>>(d1w, wt, 1024, K2_, 1024);      // d1w -> Wt[16384][1024]
    mfma_gemm_k<1><<<dim3(128, 8, 1), blk, 0, stream>>>(t2b, wt, nullptr, 1024, K2_, 1024, 1024,
                                                        d1b, X, l2a);

    // ---- classifier (f32: feeds pred/label) ----
    hipMemsetAsync(h1, 0, 524288 * sizeof(float), stream);
    gemm_sk<0><<<dim3(8, 16, 4), blk, 0, stream>>>(mg, MER, cw1, h1, 1024, 512, MER, 642);
    bias_act_k<0><<<dim3(512), blk, 0, stream>>>(h1, cb1, 524288, 512);
    colstats_k<0><<<dim3(2, 64), blk, 0, stream>>>(h1, 512, 512, nullptr, h1st);
    bn1dtrans_k<<<dim3(2, 1024), blk, 0, stream>>>(h1, 512, h1st, cg1, cbe1);

    hipMemsetAsync(h2, 0, 262144 * sizeof(float), stream);
    gemm_sk<0><<<dim3(4, 16, 4), blk, 0, stream>>>(h1, 512, cw2, h2, 1024, 256, 512, 128);
    bias_act_k<3><<<dim3(256), blk, 0, stream>>>(h2, cb2, 262144, 256);

    hipMemsetAsync(h3, 0, 131072 * sizeof(float), stream);
    gemm_sk<0><<<dim3(2, 16, 4), blk, 0, stream>>>(h2, 256, cw3, h3, 1024, 128, 256, 64);
    bias_act_k<0><<<dim3(128), blk, 0, stream>>>(h3, cb3, 131072, 128);

    gemm_k<0, 0><<<dim3(1, 16), blk, 0, stream>>>(h3, 128, cw4, cb4, h4, 1024, 2, 128);

    final_k<<<dim3(1), dim3(1024), 0, stream>>>(h4, cg2, cbe2, dscr + 12, (float*)d_out);
}